// Round 1
// baseline (314.447 us; speedup 1.0000x reference)
//
#include <hip/hip_runtime.h>
#include <hip/hip_bf16.h>
#include <cstdint>
#include <cstddef>

using bf16 = __hip_bfloat16;
typedef __bf16 bf16x8 __attribute__((ext_vector_type(8)));
typedef float f32x4 __attribute__((ext_vector_type(4)));

constexpr int BB = 4;
constexpr int TS = 8192;
constexpr int NH = 16;
constexpr int HD = 32;
constexpr int DM = 512;      // NH*HD
constexpr int NQKV = 1536;   // 3*DM
constexpr int NG = 64;       // global tokens

#define MFMA16(a, b, c) __builtin_amdgcn_mfma_f32_16x16x32_bf16((a), (b), (c), 0, 0, 0)

__device__ __forceinline__ bf16x8 ld8(const bf16* p) { return *(const bf16x8*)p; }
__device__ __forceinline__ unsigned short b16bits(bf16 v) { return __builtin_bit_cast(unsigned short, v); }

__device__ __forceinline__ void gl_lds16(const bf16* g, void* l) {
  __builtin_amdgcn_global_load_lds((const __attribute__((address_space(1))) void*)g,
                                   (__attribute__((address_space(3))) void*)l, 16, 0, 0);
}

// ---------------------------------------------------------------- prep ------
__global__ void prep_kernel(const float* __restrict__ x,
                            const float* __restrict__ Wq, const float* __restrict__ bq,
                            const float* __restrict__ Wk, const float* __restrict__ bk,
                            const float* __restrict__ Wv, const float* __restrict__ bv,
                            const float* __restrict__ Wo,
                            bf16* __restrict__ xb, bf16* __restrict__ Wt,
                            bf16* __restrict__ Wot, float* __restrict__ bqkv) {
  const int64_t stride = (int64_t)gridDim.x * blockDim.x;
  const int64_t i0 = (int64_t)blockIdx.x * blockDim.x + threadIdx.x;
  const float4* x4 = (const float4*)x;
  ushort4* xb4 = (ushort4*)xb;
  for (int64_t i = i0; i < (int64_t)BB * TS * DM / 4; i += stride) {
    float4 v = x4[i];
    ushort4 o;
    o.x = b16bits(__float2bfloat16(v.x));
    o.y = b16bits(__float2bfloat16(v.y));
    o.z = b16bits(__float2bfloat16(v.z));
    o.w = b16bits(__float2bfloat16(v.w));
    xb4[i] = o;
  }
  for (int64_t i = i0; i < (int64_t)NQKV * DM; i += stride) {
    const int n = (int)(i >> 9), k = (int)(i & 511);
    const float* W = (n < 512) ? Wq : ((n < 1024) ? Wk : Wv);
    Wt[i] = __float2bfloat16(W[(size_t)k * DM + (n & 511)]);
  }
  for (int64_t i = i0; i < (int64_t)DM * DM; i += stride) {
    const int n = (int)(i >> 9), k = (int)(i & 511);
    Wot[i] = __float2bfloat16(Wo[(size_t)k * DM + n]);
  }
  for (int64_t i = i0; i < NQKV; i += stride)
    bqkv[i] = (i < 512) ? bq[i] : ((i < 1024) ? bk[i - 512] : bv[i - 1024]);
}

// ---------------------------------------------------------------- GEMM ------
// C[M,N] = A[M,K] @ Bt[N,K]^T + bias[N].  128x128 tile, BK=64, 4 waves.
template <bool F32OUT>
__global__ __launch_bounds__(256) void gemm_bias(const bf16* __restrict__ A,
                                                 const bf16* __restrict__ Bt,
                                                 const float* __restrict__ bias,
                                                 void* __restrict__ Cv,
                                                 int M, int N, int K) {
  __shared__ __attribute__((aligned(16))) char smem[32768];
  const int tid = threadIdx.x;
  const int lane = tid & 63, wid = tid >> 6;
  const int grp = lane >> 4, col = lane & 15;
  const int NT = N >> 7;
  const int mt = blockIdx.x / NT, nt = blockIdx.x % NT;
  const int m0 = mt << 7, n0 = nt << 7;
  const int wm = wid >> 1, wn = wid & 1;
  f32x4 acc[4][4] = {};
  const int KT = K >> 6;
  for (int kt = 0; kt < KT; ++kt) {
    __syncthreads();
    #pragma unroll
    for (int c = 0; c < 4; ++c) {
      const int chunk = wid * 4 + c;              // 0..15, wave-uniform
      const int row = chunk * 8 + (lane >> 3);    // 0..127
      const int sl = lane & 7;                    // linear 16B slot in row
      const int koff = ((sl ^ (row & 7)) << 3) + (kt << 6);  // inverse-swizzled k
      gl_lds16(A + (size_t)(m0 + row) * K + koff, smem + chunk * 1024);
      gl_lds16(Bt + (size_t)(n0 + row) * K + koff, smem + 16384 + chunk * 1024);
    }
    __syncthreads();
    #pragma unroll
    for (int ks = 0; ks < 2; ++ks) {
      bf16x8 af[4], bfr[4];
      #pragma unroll
      for (int f = 0; f < 4; ++f) {
        const int ra = wm * 64 + f * 16 + col;
        af[f] = *(const bf16x8*)(smem + ra * 128 + (((ks * 4 + grp) ^ (ra & 7)) << 4));
        const int rb = wn * 64 + f * 16 + col;
        bfr[f] = *(const bf16x8*)(smem + 16384 + rb * 128 + (((ks * 4 + grp) ^ (rb & 7)) << 4));
      }
      #pragma unroll
      for (int i = 0; i < 4; ++i)
        #pragma unroll
        for (int j = 0; j < 4; ++j)
          acc[i][j] = MFMA16(af[i], bfr[j], acc[i][j]);
    }
  }
  #pragma unroll
  for (int i = 0; i < 4; ++i)
    #pragma unroll
    for (int j = 0; j < 4; ++j) {
      const int n = n0 + wn * 64 + j * 16 + col;
      const float bz = bias[n];
      #pragma unroll
      for (int r = 0; r < 4; ++r) {
        const int m = m0 + wm * 64 + i * 16 + grp * 4 + r;
        const float v = acc[i][j][r] + bz;
        if (F32OUT)
          ((float*)Cv)[(size_t)m * N + n] = v;
        else
          ((bf16*)Cv)[(size_t)m * N + n] = __float2bfloat16(v);
      }
    }
}

// ------------------------------------------------------------- vtrans -------
// vt[(b*NH+h)*HD+dv][t] = v[b,h,t,dv]; vgt[(b*NH+h)*HD+dv][g] = v[b,h,gidx[g],dv]
__global__ void vtrans_kernel(const bf16* __restrict__ qkv, const int* __restrict__ gidx,
                              bf16* __restrict__ vt, bf16* __restrict__ vgt) {
  const int64_t stride = (int64_t)gridDim.x * blockDim.x;
  const int64_t i0 = (int64_t)blockIdx.x * blockDim.x + threadIdx.x;
  for (int64_t i = i0; i < (int64_t)2048 * (TS / 8); i += stride) {
    const int row = (int)(i >> 10);     // TS/8 = 1024 chunks per row
    const int c8 = (int)(i & 1023);
    const int b = row >> 9, h = (row >> 5) & 15, dv = row & 31;
    const int t = c8 * 8;
    const bf16* src = qkv + ((size_t)(b * TS + t)) * NQKV + 1024 + h * 32 + dv;
    bf16x8 o;
    #pragma unroll
    for (int j = 0; j < 8; ++j) o[j] = *(const __bf16*)(src + (size_t)j * NQKV);
    *(bf16x8*)(vt + (size_t)row * TS + t) = o;
  }
  for (int64_t i = i0; i < (int64_t)2048 * NG; i += stride) {
    const int row = (int)(i >> 6), g = (int)(i & 63);
    const int b = row >> 9, h = (row >> 5) & 15, dv = row & 31;
    const int gi = gidx[g];
    vgt[i] = qkv[((size_t)(b * TS + gi)) * NQKV + 1024 + h * 32 + dv];
  }
}

// --------------------------------------------------------------- attn -------
// One wave per 16 queries. Local window dense 144 keys (masked to the 129-band),
// 64 global keys. P staged per-wave in LDS (padded stride), PV via MFMA.
__global__ __launch_bounds__(256) void attn_kernel(const bf16* __restrict__ qkv,
                                                   const bf16* __restrict__ vt,
                                                   const bf16* __restrict__ vgt,
                                                   const int* __restrict__ gidx,
                                                   bf16* __restrict__ ctx) {
  constexpr int PROW = 232;  // padded LDS row stride (elems): 224 used + pad
  __shared__ __attribute__((aligned(16))) bf16 sP[4][16 * PROW];
  const int tid = threadIdx.x, wid = tid >> 6, lane = tid & 63;
  const int grp = lane >> 4, col = lane & 15;
  const int bid = blockIdx.x;
  const int tile = bid & 127, h = (bid >> 7) & 15, b = bid >> 11;
  const int t0 = tile * 64 + wid * 16;
  const int kb = t0 - 64;
  bf16* myP = sP[wid];
  const bf16* base = qkv + (size_t)b * TS * NQKV;
  const bf16* kbase = base + 512 + h * 32;

  const bf16x8 qf = ld8(base + (size_t)(t0 + col) * NQKV + h * 32 + grp * 8);
  const f32x4 z = {0.f, 0.f, 0.f, 0.f};
  f32x4 s[13];
  #pragma unroll
  for (int f = 0; f < 9; ++f) {
    int pos = kb + f * 16 + col;
    int cp = min(max(pos, 0), TS - 1);
    bf16x8 kf = ld8(kbase + (size_t)cp * NQKV + grp * 8);
    s[f] = MFMA16(qf, kf, z);
  }
  #pragma unroll
  for (int f = 0; f < 4; ++f) {
    int gi = gidx[f * 16 + col];
    bf16x8 kf = ld8(kbase + (size_t)gi * NQKV + grp * 8);
    s[9 + f] = MFMA16(qf, kf, z);
  }
  const float scale = 0.17677669529663688f;  // 1/sqrt(32)
  float mx[4] = {-3e38f, -3e38f, -3e38f, -3e38f};
  #pragma unroll
  for (int f = 0; f < 13; ++f) {
    #pragma unroll
    for (int r = 0; r < 4; ++r) {
      float v = s[f][r] * scale;
      if (f < 9) {
        const int q = grp * 4 + r;
        const int j = f * 16 + col;
        const int pos = kb + j;
        const bool valid = (j >= q) & (j <= q + 128) & (pos >= 0) & (pos < TS);
        v = valid ? v : -1e30f;
      }
      s[f][r] = v;
      mx[r] = fmaxf(mx[r], v);
    }
  }
  #pragma unroll
  for (int r = 0; r < 4; ++r) {
    #pragma unroll
    for (int d = 1; d < 16; d <<= 1) mx[r] = fmaxf(mx[r], __shfl_xor(mx[r], d));
  }
  float sm[4] = {0.f, 0.f, 0.f, 0.f};
  #pragma unroll
  for (int f = 0; f < 13; ++f) {
    #pragma unroll
    for (int r = 0; r < 4; ++r) {
      float p = __expf(s[f][r] - mx[r]);
      s[f][r] = p;
      sm[r] += p;
    }
  }
  #pragma unroll
  for (int r = 0; r < 4; ++r) {
    #pragma unroll
    for (int d = 1; d < 16; d <<= 1) sm[r] += __shfl_xor(sm[r], d);
    sm[r] = 1.0f / sm[r];
  }
  // write P: local frags at j=f*16, pad zeros at 144..159, global at 160..223
  #pragma unroll
  for (int f = 0; f < 13; ++f) {
    const int j = f * 16 + col + ((f >= 9) ? 16 : 0);
    #pragma unroll
    for (int r = 0; r < 4; ++r)
      myP[(grp * 4 + r) * PROW + j] = __float2bfloat16(s[f][r]);
  }
  #pragma unroll
  for (int r = 0; r < 4; ++r)
    myP[(grp * 4 + r) * PROW + 144 + col] = __float2bfloat16(0.f);
  __threadfence_block();  // s_waitcnt lgkmcnt(0): P writes visible to own-wave reads

  f32x4 c0 = z, c1 = z;
  const bf16* vrow = vt + (size_t)((b * NH + h) * HD) * TS;
  #pragma unroll
  for (int ks = 0; ks < 5; ++ks) {
    bf16x8 pa = ld8(myP + col * PROW + ks * 32 + grp * 8);
    const int trow = kb + ks * 32 + grp * 8;  // may be <0 / >=TS: pad + P==0
    bf16x8 v0 = ld8(vrow + (size_t)col * TS + trow);
    bf16x8 v1 = ld8(vrow + (size_t)(col + 16) * TS + trow);
    c0 = MFMA16(pa, v0, c0);
    c1 = MFMA16(pa, v1, c1);
  }
  const bf16* vg = vgt + (size_t)((b * NH + h) * HD) * NG;
  #pragma unroll
  for (int ks = 0; ks < 2; ++ks) {
    bf16x8 pa = ld8(myP + col * PROW + 160 + ks * 32 + grp * 8);
    bf16x8 v0 = ld8(vg + (size_t)col * NG + ks * 32 + grp * 8);
    bf16x8 v1 = ld8(vg + (size_t)(col + 16) * NG + ks * 32 + grp * 8);
    c0 = MFMA16(pa, v0, c0);
    c1 = MFMA16(pa, v1, c1);
  }
  #pragma unroll
  for (int r = 0; r < 4; ++r) {
    const int t = t0 + grp * 4 + r;
    const size_t o = ((size_t)(b * TS + t)) * DM + h * 32;
    ctx[o + col] = __float2bfloat16(c0[r] * sm[r]);
    ctx[o + 16 + col] = __float2bfloat16(c1[r] * sm[r]);
  }
}

// ------------------------------------------------------------- launch -------
extern "C" void kernel_launch(void* const* d_in, const int* in_sizes, int n_in,
                              void* d_out, int out_size, void* d_ws, size_t ws_size,
                              hipStream_t stream) {
  (void)in_sizes; (void)n_in; (void)out_size; (void)ws_size;
  const float* x = (const float*)d_in[0];
  const float* Wq = (const float*)d_in[1];
  const float* bq = (const float*)d_in[2];
  const float* Wk = (const float*)d_in[3];
  const float* bk = (const float*)d_in[4];
  const float* Wv = (const float*)d_in[5];
  const float* bv = (const float*)d_in[6];
  const float* Wo = (const float*)d_in[7];
  const float* bo = (const float*)d_in[8];
  const int* gidx = (const int*)d_in[9];
  float* out = (float*)d_out;

  char* ws = (char*)d_ws;
  size_t off = 0;
  auto alloc = [&](size_t bytes) -> void* {
    void* p = ws + off;
    off += (bytes + 255) & ~(size_t)255;
    return p;
  };
  bf16* xb = (bf16*)alloc((size_t)BB * TS * DM * 2);       // 32 MB (reused as ctx)
  bf16* Wt = (bf16*)alloc((size_t)NQKV * DM * 2);          // 1.5 MB
  bf16* Wot = (bf16*)alloc((size_t)DM * DM * 2);           // 0.5 MB
  float* bqkv = (float*)alloc((size_t)NQKV * 4);           // 6 KB
  bf16* qkv = (bf16*)alloc((size_t)BB * TS * NQKV * 2);    // 96 MB
  bf16* vta = (bf16*)alloc(((size_t)2048 * TS + 512) * 2); // 32 MB + pad
  bf16* vgt = (bf16*)alloc((size_t)2048 * NG * 2);         // 256 KB
  bf16* ctx = xb;                                          // alias: xb dead after GEMM1
  bf16* vt = vta + 64;                                     // front pad of 64 elems

  prep_kernel<<<dim3(2048), dim3(256), 0, stream>>>(x, Wq, bq, Wk, bk, Wv, bv, Wo,
                                                    xb, Wt, Wot, bqkv);
  gemm_bias<false><<<dim3(256 * 12), dim3(256), 0, stream>>>(xb, Wt, bqkv, qkv,
                                                             BB * TS, NQKV, DM);
  vtrans_kernel<<<dim3(4096), dim3(256), 0, stream>>>(qkv, gidx, vt, vgt);
  attn_kernel<<<dim3(8192), dim3(256), 0, stream>>>(qkv, vt, vgt, gidx, ctx);
  gemm_bias<true><<<dim3(256 * 4), dim3(256), 0, stream>>>(ctx, Wot, bo, out,
                                                           BB * TS, DM, DM);
}

// Round 2
// 285.659 us; speedup vs baseline: 1.1008x; 1.1008x over previous
//
#include <hip/hip_runtime.h>
#include <hip/hip_bf16.h>
#include <cstdint>
#include <cstddef>

using bf16 = __hip_bfloat16;
typedef __bf16 bf16x8 __attribute__((ext_vector_type(8)));
typedef float f32x4 __attribute__((ext_vector_type(4)));

constexpr int BB = 4;
constexpr int TS = 8192;
constexpr int NH = 16;
constexpr int HD = 32;
constexpr int DM = 512;      // NH*HD
constexpr int NQKV = 1536;   // 3*DM
constexpr int NG = 64;       // global tokens

#define MFMA16(a, b, c) __builtin_amdgcn_mfma_f32_16x16x32_bf16((a), (b), (c), 0, 0, 0)

__device__ __forceinline__ bf16x8 ld8(const bf16* p) { return *(const bf16x8*)p; }
__device__ __forceinline__ unsigned short b16bits(bf16 v) { return __builtin_bit_cast(unsigned short, v); }

__device__ __forceinline__ void gl_lds16(const bf16* g, void* l) {
  __builtin_amdgcn_global_load_lds((const __attribute__((address_space(1))) void*)g,
                                   (__attribute__((address_space(3))) void*)l, 16, 0, 0);
}

// ---------------------------------------------------------------- prep ------
__global__ void prep_kernel(const float* __restrict__ x,
                            const float* __restrict__ Wq, const float* __restrict__ bq,
                            const float* __restrict__ Wk, const float* __restrict__ bk,
                            const float* __restrict__ Wv, const float* __restrict__ bv,
                            const float* __restrict__ Wo,
                            bf16* __restrict__ xb, bf16* __restrict__ Wt,
                            bf16* __restrict__ Wot, float* __restrict__ bqkv) {
  const int64_t stride = (int64_t)gridDim.x * blockDim.x;
  const int64_t i0 = (int64_t)blockIdx.x * blockDim.x + threadIdx.x;
  const float4* x4 = (const float4*)x;
  ushort4* xb4 = (ushort4*)xb;
  for (int64_t i = i0; i < (int64_t)BB * TS * DM / 4; i += stride) {
    float4 v = x4[i];
    ushort4 o;
    o.x = b16bits(__float2bfloat16(v.x));
    o.y = b16bits(__float2bfloat16(v.y));
    o.z = b16bits(__float2bfloat16(v.z));
    o.w = b16bits(__float2bfloat16(v.w));
    xb4[i] = o;
  }
  for (int64_t i = i0; i < (int64_t)NQKV * DM; i += stride) {
    const int n = (int)(i >> 9), k = (int)(i & 511);
    const float* W = (n < 512) ? Wq : ((n < 1024) ? Wk : Wv);
    Wt[i] = __float2bfloat16(W[(size_t)k * DM + (n & 511)]);
  }
  for (int64_t i = i0; i < (int64_t)DM * DM; i += stride) {
    const int n = (int)(i >> 9), k = (int)(i & 511);
    Wot[i] = __float2bfloat16(Wo[(size_t)k * DM + n]);
  }
  for (int64_t i = i0; i < NQKV; i += stride)
    bqkv[i] = (i < 512) ? bq[i] : ((i < 1024) ? bk[i - 512] : bv[i - 1024]);
}

// ---------------------------------------------------------------- GEMM ------
// C[M,N] = A[M,K] @ Bt[N,K]^T + bias[N].  128x128 tile, BK=64, 4 waves.
template <bool F32OUT>
__global__ __launch_bounds__(256) void gemm_bias(const bf16* __restrict__ A,
                                                 const bf16* __restrict__ Bt,
                                                 const float* __restrict__ bias,
                                                 void* __restrict__ Cv,
                                                 int M, int N, int K) {
  __shared__ __attribute__((aligned(16))) char smem[32768];
  const int tid = threadIdx.x;
  const int lane = tid & 63, wid = tid >> 6;
  const int grp = lane >> 4, col = lane & 15;
  const int NT = N >> 7;
  const int mt = blockIdx.x / NT, nt = blockIdx.x % NT;
  const int m0 = mt << 7, n0 = nt << 7;
  const int wm = wid >> 1, wn = wid & 1;
  f32x4 acc[4][4] = {};
  const int KT = K >> 6;
  for (int kt = 0; kt < KT; ++kt) {
    __syncthreads();
    #pragma unroll
    for (int c = 0; c < 4; ++c) {
      const int chunk = wid * 4 + c;              // 0..15, wave-uniform
      const int row = chunk * 8 + (lane >> 3);    // 0..127
      const int sl = lane & 7;                    // linear 16B slot in row
      const int koff = ((sl ^ (row & 7)) << 3) + (kt << 6);  // inverse-swizzled k
      gl_lds16(A + (size_t)(m0 + row) * K + koff, smem + chunk * 1024);
      gl_lds16(Bt + (size_t)(n0 + row) * K + koff, smem + 16384 + chunk * 1024);
    }
    __syncthreads();
    #pragma unroll
    for (int ks = 0; ks < 2; ++ks) {
      bf16x8 af[4], bfr[4];
      #pragma unroll
      for (int f = 0; f < 4; ++f) {
        const int ra = wm * 64 + f * 16 + col;
        af[f] = *(const bf16x8*)(smem + ra * 128 + (((ks * 4 + grp) ^ (ra & 7)) << 4));
        const int rb = wn * 64 + f * 16 + col;
        bfr[f] = *(const bf16x8*)(smem + 16384 + rb * 128 + (((ks * 4 + grp) ^ (rb & 7)) << 4));
      }
      #pragma unroll
      for (int i = 0; i < 4; ++i)
        #pragma unroll
        for (int j = 0; j < 4; ++j)
          acc[i][j] = MFMA16(af[i], bfr[j], acc[i][j]);
    }
  }
  #pragma unroll
  for (int i = 0; i < 4; ++i)
    #pragma unroll
    for (int j = 0; j < 4; ++j) {
      const int n = n0 + wn * 64 + j * 16 + col;
      const float bz = bias[n];
      #pragma unroll
      for (int r = 0; r < 4; ++r) {
        const int m = m0 + wm * 64 + i * 16 + grp * 4 + r;
        const float v = acc[i][j][r] + bz;
        if (F32OUT)
          ((float*)Cv)[(size_t)m * N + n] = v;
        else
          ((bf16*)Cv)[(size_t)m * N + n] = __float2bfloat16(v);
      }
    }
}

// ------------------------------------------------------------- vtrans -------
// vt[(b*NH+h)*HD+dv][t] = v[b,h,t,dv]; vgt[(b*NH+h)*HD+dv][g] = v[b,h,gidx[g],dv]
// Also zeroes vt's front (64) and tail (448) pad elements.
__global__ void vtrans_kernel(const bf16* __restrict__ qkv, const int* __restrict__ gidx,
                              bf16* __restrict__ vt, bf16* __restrict__ vgt) {
  const int64_t stride = (int64_t)gridDim.x * blockDim.x;
  const int64_t i0 = (int64_t)blockIdx.x * blockDim.x + threadIdx.x;
  for (int64_t i = i0; i < 512; i += stride) {
    if (i < 64) vt[i - 64] = __float2bfloat16(0.f);
    else vt[(size_t)2048 * TS + (i - 64)] = __float2bfloat16(0.f);
  }
  for (int64_t i = i0; i < (int64_t)2048 * (TS / 8); i += stride) {
    const int row = (int)(i >> 10);     // TS/8 = 1024 chunks per row
    const int c8 = (int)(i & 1023);
    const int b = row >> 9, h = (row >> 5) & 15, dv = row & 31;
    const int t = c8 * 8;
    const bf16* src = qkv + ((size_t)(b * TS + t)) * NQKV + 1024 + h * 32 + dv;
    bf16x8 o;
    #pragma unroll
    for (int j = 0; j < 8; ++j) o[j] = *(const __bf16*)(src + (size_t)j * NQKV);
    *(bf16x8*)(vt + (size_t)row * TS + t) = o;
  }
  for (int64_t i = i0; i < (int64_t)2048 * NG; i += stride) {
    const int row = (int)(i >> 6), g = (int)(i & 63);
    const int b = row >> 9, h = (row >> 5) & 15, dv = row & 31;
    const int gi = gidx[g];
    vgt[i] = qkv[((size_t)(b * TS + gi)) * NQKV + 1024 + h * 32 + dv];
  }
}

// --------------------------------------------------------------- attn -------
// Block = 64 queries of one (b,h); 4 waves x 16 queries. All K/V fragments are
// staged cooperatively into LDS with coalesced 16B chunks:
//   sK  [192][40]  local K window (rows kb_blk..kb_blk+191, clamped)
//   sKg [64][40]   gathered global K
//   sV  [32][216]  V^T window (216 keys; tail reads land in zeroed vt pads)
//   sVg [32][88]   global V^T
//   sP  [4][16*232] per-wave P staging (unchanged)
// Padded strides give <=2-way LDS bank aliasing (free).
__global__ __launch_bounds__(256) void attn_kernel(const bf16* __restrict__ qkv,
                                                   const bf16* __restrict__ vt,
                                                   const bf16* __restrict__ vgt,
                                                   const int* __restrict__ gidx,
                                                   bf16* __restrict__ ctx) {
  constexpr int PROW = 232;
  constexpr int KST = 40;    // sK/sKg row stride (elems)
  constexpr int VST = 216;   // sV row stride (elems)
  constexpr int VGST = 88;   // sVg row stride (elems)
  __shared__ __attribute__((aligned(16))) bf16 sK[192 * KST];
  __shared__ __attribute__((aligned(16))) bf16 sKg[64 * KST];
  __shared__ __attribute__((aligned(16))) bf16 sV[32 * VST];
  __shared__ __attribute__((aligned(16))) bf16 sVg[32 * VGST];
  __shared__ __attribute__((aligned(16))) bf16 sP[4][16 * PROW];

  const int tid = threadIdx.x, wid = tid >> 6, lane = tid & 63;
  const int grp = lane >> 4, col = lane & 15;
  // XCD-aware swizzle: 8192 blocks = 8 XCDs x 1024; keeps one (b,h)'s tiles
  // (overlapping K windows) on one XCD's L2.
  const int bid = (blockIdx.x & 7) * 1024 + (blockIdx.x >> 3);
  const int tile = bid & 127, h = (bid >> 7) & 15, b = bid >> 11;
  const int t0b = tile * 64;          // block's first query
  const int kbb = t0b - 64;           // block's first local key (may be <0)
  const int bh = b * NH + h;
  const bf16* base = qkv + (size_t)b * TS * NQKV;
  const bf16* kpl = base + 512 + h * 32;   // K plane

  // ---- cooperative staging (all coalesced 16B chunks) ----
  #pragma unroll
  for (int it = 0; it < 3; ++it) {           // sK: 768 chunks
    const int idx = it * 256 + tid;
    const int row = idx >> 2, part = idx & 3;
    const int tok = min(max(kbb + row, 0), TS - 1);
    *(bf16x8*)(sK + row * KST + part * 8) = ld8(kpl + (size_t)tok * NQKV + part * 8);
  }
  {
    const bf16* vr = vt + (size_t)(bh * HD + (tid >> 3)) * TS + kbb;
    #pragma unroll
    for (int i = 0; i < 4; ++i) {            // sV: 32 rows x 27 chunks
      const int c = i * 8 + (tid & 7);
      if (c < 27) *(bf16x8*)(sV + (tid >> 3) * VST + c * 8) = ld8(vr + c * 8);
    }
  }
  {
    const int row = tid >> 2, part = tid & 3;  // sKg: 256 chunks
    const int gi = gidx[row];
    *(bf16x8*)(sKg + row * KST + part * 8) = ld8(kpl + (size_t)gi * NQKV + part * 8);
  }
  {
    const int row = tid >> 3, c = tid & 7;     // sVg: 256 chunks
    *(bf16x8*)(sVg + row * VGST + c * 8) = ld8(vgt + (size_t)(bh * HD + row) * NG + c * 8);
  }
  __syncthreads();

  // ---- per-wave compute ----
  const int qt = t0b + wid * 16;      // wave's first query
  const int offw = wid * 16;          // wave window start inside sK/sV
  bf16* myP = sP[wid];

  const bf16x8 qf = ld8(base + (size_t)(qt + col) * NQKV + h * 32 + grp * 8);
  const f32x4 z = {0.f, 0.f, 0.f, 0.f};
  f32x4 s[13];
  #pragma unroll
  for (int f = 0; f < 9; ++f) {
    bf16x8 kf = ld8(sK + (offw + f * 16 + col) * KST + grp * 8);
    s[f] = MFMA16(qf, kf, z);
  }
  #pragma unroll
  for (int f = 0; f < 4; ++f) {
    bf16x8 kf = ld8(sKg + (f * 16 + col) * KST + grp * 8);
    s[9 + f] = MFMA16(qf, kf, z);
  }
  const float scale = 0.17677669529663688f;  // 1/sqrt(32)
  float mx[4] = {-3e38f, -3e38f, -3e38f, -3e38f};
  #pragma unroll
  for (int f = 0; f < 13; ++f) {
    #pragma unroll
    for (int r = 0; r < 4; ++r) {
      float v = s[f][r] * scale;
      if (f < 9) {
        const int q = grp * 4 + r;
        const int j = f * 16 + col;
        const int pos = qt - 64 + j;
        const bool valid = (j >= q) & (j <= q + 128) & (pos >= 0) & (pos < TS);
        v = valid ? v : -1e30f;
      }
      s[f][r] = v;
      mx[r] = fmaxf(mx[r], v);
    }
  }
  #pragma unroll
  for (int r = 0; r < 4; ++r) {
    #pragma unroll
    for (int d = 1; d < 16; d <<= 1) mx[r] = fmaxf(mx[r], __shfl_xor(mx[r], d));
  }
  float sm[4] = {0.f, 0.f, 0.f, 0.f};
  #pragma unroll
  for (int f = 0; f < 13; ++f) {
    #pragma unroll
    for (int r = 0; r < 4; ++r) {
      float p = __expf(s[f][r] - mx[r]);
      s[f][r] = p;
      sm[r] += p;
    }
  }
  #pragma unroll
  for (int r = 0; r < 4; ++r) {
    #pragma unroll
    for (int d = 1; d < 16; d <<= 1) sm[r] += __shfl_xor(sm[r], d);
    sm[r] = 1.0f / sm[r];
  }
  // write P: local frags at j=f*16, zero pad at 144..159, global at 160..223
  #pragma unroll
  for (int f = 0; f < 13; ++f) {
    const int j = f * 16 + col + ((f >= 9) ? 16 : 0);
    #pragma unroll
    for (int r = 0; r < 4; ++r)
      myP[(grp * 4 + r) * PROW + j] = __float2bfloat16(s[f][r]);
  }
  #pragma unroll
  for (int r = 0; r < 4; ++r)
    myP[(grp * 4 + r) * PROW + 144 + col] = __float2bfloat16(0.f);
  __threadfence_block();

  f32x4 c0 = z, c1 = z;
  #pragma unroll
  for (int ks = 0; ks < 5; ++ks) {
    bf16x8 pa = ld8(myP + col * PROW + ks * 32 + grp * 8);
    const int kk = offw + ks * 32 + grp * 8;    // <= 207, within staged 216
    bf16x8 v0 = ld8(sV + col * VST + kk);
    bf16x8 v1 = ld8(sV + (col + 16) * VST + kk);
    c0 = MFMA16(pa, v0, c0);
    c1 = MFMA16(pa, v1, c1);
  }
  #pragma unroll
  for (int ks = 0; ks < 2; ++ks) {
    bf16x8 pa = ld8(myP + col * PROW + 160 + ks * 32 + grp * 8);
    bf16x8 v0 = ld8(sVg + col * VGST + ks * 32 + grp * 8);
    bf16x8 v1 = ld8(sVg + (col + 16) * VGST + ks * 32 + grp * 8);
    c0 = MFMA16(pa, v0, c0);
    c1 = MFMA16(pa, v1, c1);
  }
  #pragma unroll
  for (int r = 0; r < 4; ++r) {
    const int t = qt + grp * 4 + r;
    const size_t o = ((size_t)(b * TS + t)) * DM + h * 32;
    ctx[o + col] = __float2bfloat16(c0[r] * sm[r]);
    ctx[o + 16 + col] = __float2bfloat16(c1[r] * sm[r]);
  }
}

// ------------------------------------------------------------- launch -------
extern "C" void kernel_launch(void* const* d_in, const int* in_sizes, int n_in,
                              void* d_out, int out_size, void* d_ws, size_t ws_size,
                              hipStream_t stream) {
  (void)in_sizes; (void)n_in; (void)out_size; (void)ws_size;
  const float* x = (const float*)d_in[0];
  const float* Wq = (const float*)d_in[1];
  const float* bq = (const float*)d_in[2];
  const float* Wk = (const float*)d_in[3];
  const float* bk = (const float*)d_in[4];
  const float* Wv = (const float*)d_in[5];
  const float* bv = (const float*)d_in[6];
  const float* Wo = (const float*)d_in[7];
  const float* bo = (const float*)d_in[8];
  const int* gidx = (const int*)d_in[9];
  float* out = (float*)d_out;

  char* ws = (char*)d_ws;
  size_t off = 0;
  auto alloc = [&](size_t bytes) -> void* {
    void* p = ws + off;
    off += (bytes + 255) & ~(size_t)255;
    return p;
  };
  bf16* xb = (bf16*)alloc((size_t)BB * TS * DM * 2);       // 32 MB (reused as ctx)
  bf16* Wt = (bf16*)alloc((size_t)NQKV * DM * 2);          // 1.5 MB
  bf16* Wot = (bf16*)alloc((size_t)DM * DM * 2);           // 0.5 MB
  float* bqkv = (float*)alloc((size_t)NQKV * 4);           // 6 KB
  bf16* qkv = (bf16*)alloc((size_t)BB * TS * NQKV * 2);    // 96 MB
  bf16* vta = (bf16*)alloc(((size_t)2048 * TS + 512) * 2); // 32 MB + pad
  bf16* vgt = (bf16*)alloc((size_t)2048 * NG * 2);         // 256 KB
  bf16* ctx = xb;                                          // alias: xb dead after GEMM1
  bf16* vt = vta + 64;                                     // front pad of 64 elems

  prep_kernel<<<dim3(2048), dim3(256), 0, stream>>>(x, Wq, bq, Wk, bk, Wv, bv, Wo,
                                                    xb, Wt, Wot, bqkv);
  gemm_bias<false><<<dim3(256 * 12), dim3(256), 0, stream>>>(xb, Wt, bqkv, qkv,
                                                             BB * TS, NQKV, DM);
  vtrans_kernel<<<dim3(4096), dim3(256), 0, stream>>>(qkv, gidx, vt, vgt);
  attn_kernel<<<dim3(8192), dim3(256), 0, stream>>>(qkv, vt, vgt, gidx, ctx);
  gemm_bias<true><<<dim3(256 * 4), dim3(256), 0, stream>>>(ctx, Wot, bo, out,
                                                           BB * TS, DM, DM);
}

// Round 3
// 244.857 us; speedup vs baseline: 1.2842x; 1.1666x over previous
//
#include <hip/hip_runtime.h>
#include <hip/hip_bf16.h>
#include <cstdint>
#include <cstddef>

using bf16 = __hip_bfloat16;
typedef __bf16 bf16x8 __attribute__((ext_vector_type(8)));
typedef float f32x4 __attribute__((ext_vector_type(4)));

constexpr int BB = 4;
constexpr int TS = 8192;
constexpr int NH = 16;
constexpr int HD = 32;
constexpr int DM = 512;      // NH*HD
constexpr int NQKV = 1536;   // 3*DM
constexpr int NG = 64;       // global tokens

#define MFMA16(a, b, c) __builtin_amdgcn_mfma_f32_16x16x32_bf16((a), (b), (c), 0, 0, 0)

__device__ __forceinline__ bf16x8 ld8(const bf16* p) { return *(const bf16x8*)p; }
__device__ __forceinline__ unsigned short b16bits(bf16 v) { return __builtin_bit_cast(unsigned short, v); }

__device__ __forceinline__ void gl_lds16(const bf16* g, void* l) {
  __builtin_amdgcn_global_load_lds((const __attribute__((address_space(1))) void*)g,
                                   (__attribute__((address_space(3))) void*)l, 16, 0, 0);
}

// ---------------------------------------------------------------- prep ------
__global__ void prep_kernel(const float* __restrict__ x,
                            const float* __restrict__ Wq, const float* __restrict__ bq,
                            const float* __restrict__ Wk, const float* __restrict__ bk,
                            const float* __restrict__ Wv, const float* __restrict__ bv,
                            const float* __restrict__ Wo,
                            bf16* __restrict__ xb, bf16* __restrict__ Wt,
                            bf16* __restrict__ Wot, float* __restrict__ bqkv) {
  const int64_t stride = (int64_t)gridDim.x * blockDim.x;
  const int64_t i0 = (int64_t)blockIdx.x * blockDim.x + threadIdx.x;
  const float4* x4 = (const float4*)x;
  ushort4* xb4 = (ushort4*)xb;
  for (int64_t i = i0; i < (int64_t)BB * TS * DM / 4; i += stride) {
    float4 v = x4[i];
    ushort4 o;
    o.x = b16bits(__float2bfloat16(v.x));
    o.y = b16bits(__float2bfloat16(v.y));
    o.z = b16bits(__float2bfloat16(v.z));
    o.w = b16bits(__float2bfloat16(v.w));
    xb4[i] = o;
  }
  for (int64_t i = i0; i < (int64_t)NQKV * DM; i += stride) {
    const int n = (int)(i >> 9), k = (int)(i & 511);
    const float* W = (n < 512) ? Wq : ((n < 1024) ? Wk : Wv);
    Wt[i] = __float2bfloat16(W[(size_t)k * DM + (n & 511)]);
  }
  for (int64_t i = i0; i < (int64_t)DM * DM; i += stride) {
    const int n = (int)(i >> 9), k = (int)(i & 511);
    Wot[i] = __float2bfloat16(Wo[(size_t)k * DM + n]);
  }
  for (int64_t i = i0; i < NQKV; i += stride)
    bqkv[i] = (i < 512) ? bq[i] : ((i < 1024) ? bk[i - 512] : bv[i - 1024]);
}

// ---------------------------------------------------------------- GEMM ------
// C[M,N] = A[M,K] @ Bt[N,K]^T + bias[N].  128x128 tile, BK=64, 4 waves.
// XCD-aware bid swizzle (grid must be divisible by 8; cpx = grid/8).
// WVT: for n>=1024 (the V third) also scatter-write vt[b*512 + (n&511)][t].
template <bool F32OUT, bool WVT>
__global__ __launch_bounds__(256) void gemm_bias(const bf16* __restrict__ A,
                                                 const bf16* __restrict__ Bt,
                                                 const float* __restrict__ bias,
                                                 void* __restrict__ Cv,
                                                 bf16* __restrict__ vt,
                                                 int M, int N, int K, int cpx) {
  __shared__ __attribute__((aligned(16))) char smem[32768];
  const int tid = threadIdx.x;
  const int lane = tid & 63, wid = tid >> 6;
  const int grp = lane >> 4, col = lane & 15;
  const int bid = (blockIdx.x & 7) * cpx + (blockIdx.x >> 3);
  const int NT = N >> 7;
  const int mt = bid / NT, nt = bid % NT;
  const int m0 = mt << 7, n0 = nt << 7;
  const int wm = wid >> 1, wn = wid & 1;
  f32x4 acc[4][4] = {};
  const int KT = K >> 6;
  for (int kt = 0; kt < KT; ++kt) {
    __syncthreads();
    #pragma unroll
    for (int c = 0; c < 4; ++c) {
      const int chunk = wid * 4 + c;              // 0..15, wave-uniform
      const int row = chunk * 8 + (lane >> 3);    // 0..127
      const int sl = lane & 7;                    // linear 16B slot in row
      const int koff = ((sl ^ (row & 7)) << 3) + (kt << 6);  // inverse-swizzled k
      gl_lds16(A + (size_t)(m0 + row) * K + koff, smem + chunk * 1024);
      gl_lds16(Bt + (size_t)(n0 + row) * K + koff, smem + 16384 + chunk * 1024);
    }
    __syncthreads();
    #pragma unroll
    for (int ks = 0; ks < 2; ++ks) {
      bf16x8 af[4], bfr[4];
      #pragma unroll
      for (int f = 0; f < 4; ++f) {
        const int ra = wm * 64 + f * 16 + col;
        af[f] = *(const bf16x8*)(smem + ra * 128 + (((ks * 4 + grp) ^ (ra & 7)) << 4));
        const int rb = wn * 64 + f * 16 + col;
        bfr[f] = *(const bf16x8*)(smem + 16384 + rb * 128 + (((ks * 4 + grp) ^ (rb & 7)) << 4));
      }
      #pragma unroll
      for (int i = 0; i < 4; ++i)
        #pragma unroll
        for (int j = 0; j < 4; ++j)
          acc[i][j] = MFMA16(af[i], bfr[j], acc[i][j]);
    }
  }
  const bool wv = WVT && (n0 >= 1024);
  #pragma unroll
  for (int i = 0; i < 4; ++i)
    #pragma unroll
    for (int j = 0; j < 4; ++j) {
      const int n = n0 + wn * 64 + j * 16 + col;
      const float bz = bias[n];
      #pragma unroll
      for (int r = 0; r < 4; ++r) {
        const int m = m0 + wm * 64 + i * 16 + grp * 4 + r;
        const float v = acc[i][j][r] + bz;
        if (F32OUT) {
          ((float*)Cv)[(size_t)m * N + n] = v;
        } else {
          const bf16 vb = __float2bfloat16(v);
          ((bf16*)Cv)[(size_t)m * N + n] = vb;
          if (wv) {
            const int b = m >> 13, t = m & 8191;
            vt[(size_t)(b * DM + (n & 511)) * TS + t] = vb;
          }
        }
      }
    }
}

// --------------------------------------------------------------- vgt --------
// vgt[(b*NH+h)*HD+dv][g] = v[b,h,gidx[g],dv]; zeroes vt front/tail pads.
__global__ void vgt_kernel(const bf16* __restrict__ qkv, const int* __restrict__ gidx,
                           bf16* __restrict__ vt, bf16* __restrict__ vgt) {
  const int64_t stride = (int64_t)gridDim.x * blockDim.x;
  const int64_t i0 = (int64_t)blockIdx.x * blockDim.x + threadIdx.x;
  for (int64_t i = i0; i < 512; i += stride) {
    if (i < 64) vt[i - 64] = __float2bfloat16(0.f);
    else vt[(size_t)2048 * TS + (i - 64)] = __float2bfloat16(0.f);
  }
  for (int64_t i = i0; i < (int64_t)2048 * NG; i += stride) {
    const int row = (int)(i >> 6), g = (int)(i & 63);
    const int b = row >> 9, h = (row >> 5) & 15, dv = row & 31;
    const int gi = gidx[g];
    vgt[i] = qkv[((size_t)(b * TS + gi)) * NQKV + 1024 + h * 32 + dv];
  }
}

// --------------------------------------------------------------- attn -------
// Block = 64 queries of one (b,h); 4 waves x 16 queries.
// LDS (single 50176 B buffer, sP overlays sK/sKg after a barrier):
//   sV  [32][216]   V^T window               (13824 B)
//   sVg [32][88]    global V^T               ( 5632 B)
//   sK  [192][32]   local K, XOR slot swizzle(12288 B)  <-+ overlaid by
//   sKg [64][32]    global K, XOR swizzle    ( 4096 B)  <-+ sP [4][16*240] (30720 B)
__global__ __launch_bounds__(256) void attn_kernel(const bf16* __restrict__ qkv,
                                                   const bf16* __restrict__ vt,
                                                   const bf16* __restrict__ vgt,
                                                   const int* __restrict__ gidx,
                                                   bf16* __restrict__ ctx) {
  constexpr int PROW = 240;  // row offset = 120 dwords == 24 mod 32 -> grp bank
                             // offsets {0,24,16,8}: conflict-free P writes
  constexpr int VST = 216;
  constexpr int VGST = 88;
  __shared__ __attribute__((aligned(16))) char smem[50176];
  bf16* sV = (bf16*)smem;
  bf16* sVg = (bf16*)(smem + 13824);
  bf16* sK = (bf16*)(smem + 19456);
  bf16* sKg = (bf16*)(smem + 31744);
  bf16* sP = (bf16*)(smem + 19456);  // overlay

  const int tid = threadIdx.x, wid = tid >> 6, lane = tid & 63;
  const int grp = lane >> 4, col = lane & 15;
  const int bid = (blockIdx.x & 7) * 1024 + (blockIdx.x >> 3);
  const int tile = bid & 127, h = (bid >> 7) & 15, b = bid >> 11;
  const int t0b = tile * 64;
  const int kbb = t0b - 64;
  const int bh = b * NH + h;
  const bf16* base = qkv + (size_t)b * TS * NQKV;
  const bf16* kpl = base + 512 + h * 32;

  // ---- cooperative staging ----
  #pragma unroll
  for (int it = 0; it < 3; ++it) {             // sK: 768 16B chunks, direct-to-LDS
    const int idx = it * 256 + tid;
    const int row = idx >> 2, part = idx & 3;
    const int tok = min(max(kbb + row, 0), TS - 1);
    gl_lds16(kpl + (size_t)tok * NQKV + ((part ^ (row & 3)) << 3), sK + idx * 8);
  }
  {
    const int row = tid >> 2, part = tid & 3;  // sKg: 256 chunks, direct-to-LDS
    const int gi = gidx[row];
    gl_lds16(kpl + (size_t)gi * NQKV + ((part ^ (row & 3)) << 3), sKg + tid * 8);
  }
  {
    const bf16* vr = vt + (size_t)(bh * HD + (tid >> 3)) * TS + kbb;
    #pragma unroll
    for (int i = 0; i < 4; ++i) {              // sV: 32 rows x 27 chunks
      const int c = i * 8 + (tid & 7);
      if (c < 27) *(bf16x8*)(sV + (tid >> 3) * VST + c * 8) = ld8(vr + c * 8);
    }
  }
  {
    const int row = tid >> 3, c = tid & 7;     // sVg: 256 chunks
    *(bf16x8*)(sVg + row * VGST + c * 8) = ld8(vgt + (size_t)(bh * HD + row) * NG + c * 8);
  }
  __syncthreads();

  // ---- per-wave compute ----
  const int qt = t0b + wid * 16;
  const int offw = wid * 16;
  bf16* myP = sP + wid * 16 * PROW;

  const bf16x8 qf = ld8(base + (size_t)(qt + col) * NQKV + h * 32 + grp * 8);
  const f32x4 z = {0.f, 0.f, 0.f, 0.f};
  f32x4 s[13];
  #pragma unroll
  for (int f = 0; f < 9; ++f) {
    const int row = offw + f * 16 + col;
    bf16x8 kf = ld8(sK + row * 32 + ((grp ^ (row & 3)) << 3));
    s[f] = MFMA16(qf, kf, z);
  }
  #pragma unroll
  for (int f = 0; f < 4; ++f) {
    const int row = f * 16 + col;
    bf16x8 kf = ld8(sKg + row * 32 + ((grp ^ (row & 3)) << 3));
    s[9 + f] = MFMA16(qf, kf, z);
  }
  const float scale = 0.17677669529663688f;  // 1/sqrt(32)
  float mx[4] = {-3e38f, -3e38f, -3e38f, -3e38f};
  const bool interior = (tile >= 1) & (tile <= 126);
  if (interior) {
    // band masks reduce to: f==0 -> col>=q, f==8 -> col<=q; f=1..7 all valid.
    #pragma unroll
    for (int f = 0; f < 13; ++f) {
      #pragma unroll
      for (int r = 0; r < 4; ++r) {
        float v = s[f][r] * scale;
        if (f == 0) v = (col >= grp * 4 + r) ? v : -1e30f;
        if (f == 8) v = (col <= grp * 4 + r) ? v : -1e30f;
        s[f][r] = v;
        mx[r] = fmaxf(mx[r], v);
      }
    }
  } else {
    #pragma unroll
    for (int f = 0; f < 13; ++f) {
      #pragma unroll
      for (int r = 0; r < 4; ++r) {
        float v = s[f][r] * scale;
        if (f < 9) {
          const int q = grp * 4 + r;
          const int j = f * 16 + col;
          const int pos = qt - 64 + j;
          const bool valid = (j >= q) & (j <= q + 128) & (pos >= 0) & (pos < TS);
          v = valid ? v : -1e30f;
        }
        s[f][r] = v;
        mx[r] = fmaxf(mx[r], v);
      }
    }
  }
  #pragma unroll
  for (int r = 0; r < 4; ++r) {
    #pragma unroll
    for (int d = 1; d < 16; d <<= 1) mx[r] = fmaxf(mx[r], __shfl_xor(mx[r], d));
  }
  float sm[4] = {0.f, 0.f, 0.f, 0.f};
  #pragma unroll
  for (int f = 0; f < 13; ++f) {
    #pragma unroll
    for (int r = 0; r < 4; ++r) {
      float p = __expf(s[f][r] - mx[r]);
      s[f][r] = p;
      sm[r] += p;
    }
  }
  #pragma unroll
  for (int r = 0; r < 4; ++r) {
    #pragma unroll
    for (int d = 1; d < 16; d <<= 1) sm[r] += __shfl_xor(sm[r], d);
    sm[r] = 1.0f / sm[r];
  }
  __syncthreads();  // all waves done reading sK/sKg; safe to overlay with sP

  // write P: local frags at j=f*16, zero pad at 144..159, global at 160..223
  #pragma unroll
  for (int f = 0; f < 13; ++f) {
    const int j = f * 16 + col + ((f >= 9) ? 16 : 0);
    #pragma unroll
    for (int r = 0; r < 4; ++r)
      myP[(grp * 4 + r) * PROW + j] = __float2bfloat16(s[f][r]);
  }
  #pragma unroll
  for (int r = 0; r < 4; ++r)
    myP[(grp * 4 + r) * PROW + 144 + col] = __float2bfloat16(0.f);
  __threadfence_block();

  f32x4 c0 = z, c1 = z;
  #pragma unroll
  for (int ks = 0; ks < 5; ++ks) {
    bf16x8 pa = ld8(myP + col * PROW + ks * 32 + grp * 8);
    const int kk = offw + ks * 32 + grp * 8;    // <= 207, within staged 216
    bf16x8 v0 = ld8(sV + col * VST + kk);
    bf16x8 v1 = ld8(sV + (col + 16) * VST + kk);
    c0 = MFMA16(pa, v0, c0);
    c1 = MFMA16(pa, v1, c1);
  }
  #pragma unroll
  for (int ks = 0; ks < 2; ++ks) {
    bf16x8 pa = ld8(myP + col * PROW + 160 + ks * 32 + grp * 8);
    bf16x8 v0 = ld8(sVg + col * VGST + ks * 32 + grp * 8);
    bf16x8 v1 = ld8(sVg + (col + 16) * VGST + ks * 32 + grp * 8);
    c0 = MFMA16(pa, v0, c0);
    c1 = MFMA16(pa, v1, c1);
  }
  #pragma unroll
  for (int r = 0; r < 4; ++r) {
    const int t = qt + grp * 4 + r;
    const size_t o = ((size_t)(b * TS + t)) * DM + h * 32;
    ctx[o + col] = __float2bfloat16(c0[r] * sm[r]);
    ctx[o + 16 + col] = __float2bfloat16(c1[r] * sm[r]);
  }
}

// ------------------------------------------------------------- launch -------
extern "C" void kernel_launch(void* const* d_in, const int* in_sizes, int n_in,
                              void* d_out, int out_size, void* d_ws, size_t ws_size,
                              hipStream_t stream) {
  (void)in_sizes; (void)n_in; (void)out_size; (void)ws_size;
  const float* x = (const float*)d_in[0];
  const float* Wq = (const float*)d_in[1];
  const float* bq = (const float*)d_in[2];
  const float* Wk = (const float*)d_in[3];
  const float* bk = (const float*)d_in[4];
  const float* Wv = (const float*)d_in[5];
  const float* bv = (const float*)d_in[6];
  const float* Wo = (const float*)d_in[7];
  const float* bo = (const float*)d_in[8];
  const int* gidx = (const int*)d_in[9];
  float* out = (float*)d_out;

  char* ws = (char*)d_ws;
  size_t off = 0;
  auto alloc = [&](size_t bytes) -> void* {
    void* p = ws + off;
    off += (bytes + 255) & ~(size_t)255;
    return p;
  };
  bf16* xb = (bf16*)alloc((size_t)BB * TS * DM * 2);       // 32 MB (reused as ctx)
  bf16* Wt = (bf16*)alloc((size_t)NQKV * DM * 2);          // 1.5 MB
  bf16* Wot = (bf16*)alloc((size_t)DM * DM * 2);           // 0.5 MB
  float* bqkv = (float*)alloc((size_t)NQKV * 4);           // 6 KB
  bf16* qkv = (bf16*)alloc((size_t)BB * TS * NQKV * 2);    // 96 MB
  bf16* vta = (bf16*)alloc(((size_t)2048 * TS + 512) * 2); // 32 MB + pad
  bf16* vgt = (bf16*)alloc((size_t)2048 * NG * 2);         // 256 KB
  bf16* ctx = xb;                                          // alias: xb dead after GEMM1
  bf16* vt = vta + 64;                                     // front pad of 64 elems

  prep_kernel<<<dim3(2048), dim3(256), 0, stream>>>(x, Wq, bq, Wk, bk, Wv, bv, Wo,
                                                    xb, Wt, Wot, bqkv);
  gemm_bias<false, true><<<dim3(3072), dim3(256), 0, stream>>>(xb, Wt, bqkv, qkv, vt,
                                                               BB * TS, NQKV, DM, 384);
  vgt_kernel<<<dim3(512), dim3(256), 0, stream>>>(qkv, gidx, vt, vgt);
  attn_kernel<<<dim3(8192), dim3(256), 0, stream>>>(qkv, vt, vgt, gidx, ctx);
  gemm_bias<true, false><<<dim3(1024), dim3(256), 0, stream>>>(ctx, Wot, bo, out, nullptr,
                                                               BB * TS, DM, DM, 128);
}

// Round 4
// 210.401 us; speedup vs baseline: 1.4945x; 1.1638x over previous
//
#include <hip/hip_runtime.h>
#include <hip/hip_bf16.h>
#include <cstdint>
#include <cstddef>

using bf16 = __hip_bfloat16;
typedef __bf16 bf16x8 __attribute__((ext_vector_type(8)));
typedef float f32x4 __attribute__((ext_vector_type(4)));

constexpr int BB = 4;
constexpr int TS = 8192;
constexpr int NH = 16;
constexpr int HD = 32;
constexpr int DM = 512;      // NH*HD
constexpr int NQKV = 1536;   // 3*DM
constexpr int NG = 64;       // global tokens

#define MFMA16(a, b, c) __builtin_amdgcn_mfma_f32_16x16x32_bf16((a), (b), (c), 0, 0, 0)

__device__ __forceinline__ bf16x8 ld8(const bf16* p) { return *(const bf16x8*)p; }
__device__ __forceinline__ unsigned short b16bits(bf16 v) { return __builtin_bit_cast(unsigned short, v); }

__device__ __forceinline__ void gl_lds16(const bf16* g, void* l) {
  __builtin_amdgcn_global_load_lds((const __attribute__((address_space(1))) void*)g,
                                   (__attribute__((address_space(3))) void*)l, 16, 0, 0);
}

// ---------------------------------------------------------------- prep ------
__global__ void prep_kernel(const float* __restrict__ x,
                            const float* __restrict__ Wq, const float* __restrict__ bq,
                            const float* __restrict__ Wk, const float* __restrict__ bk,
                            const float* __restrict__ Wv, const float* __restrict__ bv,
                            const float* __restrict__ Wo,
                            bf16* __restrict__ xb, bf16* __restrict__ Wt,
                            bf16* __restrict__ Wot, float* __restrict__ bqkv) {
  const int64_t stride = (int64_t)gridDim.x * blockDim.x;
  const int64_t i0 = (int64_t)blockIdx.x * blockDim.x + threadIdx.x;
  const float4* x4 = (const float4*)x;
  ushort4* xb4 = (ushort4*)xb;
  for (int64_t i = i0; i < (int64_t)BB * TS * DM / 4; i += stride) {
    float4 v = x4[i];
    ushort4 o;
    o.x = b16bits(__float2bfloat16(v.x));
    o.y = b16bits(__float2bfloat16(v.y));
    o.z = b16bits(__float2bfloat16(v.z));
    o.w = b16bits(__float2bfloat16(v.w));
    xb4[i] = o;
  }
  for (int64_t i = i0; i < (int64_t)NQKV * DM; i += stride) {
    const int n = (int)(i >> 9), k = (int)(i & 511);
    const float* W = (n < 512) ? Wq : ((n < 1024) ? Wk : Wv);
    Wt[i] = __float2bfloat16(W[(size_t)k * DM + (n & 511)]);
  }
  for (int64_t i = i0; i < (int64_t)DM * DM; i += stride) {
    const int n = (int)(i >> 9), k = (int)(i & 511);
    Wot[i] = __float2bfloat16(Wo[(size_t)k * DM + n]);
  }
  for (int64_t i = i0; i < NQKV; i += stride)
    bqkv[i] = (i < 512) ? bq[i] : ((i < 1024) ? bk[i - 512] : bv[i - 1024]);
}

// ---------------------------------------------------------------- GEMM ------
// C[M,N] = A[M,K] @ Bt[N,K]^T + bias[N].  128x128 tile, BK=64, 4 waves.
// XCD-aware bid swizzle (grid must be divisible by 8; cpx = grid/8).
// WVT: for n0>=1024 (the V third) the tile is NOT written to C; instead it is
// transposed through LDS (bf16, stride 136, XOR-16 swizzle) and written to
// vt[b*512 + (n&511)][t] in 128B-contiguous per-thread chunks (coalesced).
template <bool F32OUT, bool WVT>
__global__ __launch_bounds__(256) void gemm_bias(const bf16* __restrict__ A,
                                                 const bf16* __restrict__ Bt,
                                                 const float* __restrict__ bias,
                                                 void* __restrict__ Cv,
                                                 bf16* __restrict__ vt,
                                                 int M, int N, int K, int cpx) {
  constexpr int SMEM = WVT ? 35072 : 32768;  // transpose needs 128*136*2=34816
  __shared__ __attribute__((aligned(16))) char smem[SMEM];
  const int tid = threadIdx.x;
  const int lane = tid & 63, wid = tid >> 6;
  const int grp = lane >> 4, col = lane & 15;
  const int bid = (blockIdx.x & 7) * cpx + (blockIdx.x >> 3);
  const int NT = N >> 7;
  const int mt = bid / NT, nt = bid % NT;
  const int m0 = mt << 7, n0 = nt << 7;
  const int wm = wid >> 1, wn = wid & 1;
  f32x4 acc[4][4] = {};
  const int KT = K >> 6;
  for (int kt = 0; kt < KT; ++kt) {
    __syncthreads();
    #pragma unroll
    for (int c = 0; c < 4; ++c) {
      const int chunk = wid * 4 + c;              // 0..15, wave-uniform
      const int row = chunk * 8 + (lane >> 3);    // 0..127
      const int sl = lane & 7;                    // linear 16B slot in row
      const int koff = ((sl ^ (row & 7)) << 3) + (kt << 6);  // inverse-swizzled k
      gl_lds16(A + (size_t)(m0 + row) * K + koff, smem + chunk * 1024);
      gl_lds16(Bt + (size_t)(n0 + row) * K + koff, smem + 16384 + chunk * 1024);
    }
    __syncthreads();
    #pragma unroll
    for (int ks = 0; ks < 2; ++ks) {
      bf16x8 af[4], bfr[4];
      #pragma unroll
      for (int f = 0; f < 4; ++f) {
        const int ra = wm * 64 + f * 16 + col;
        af[f] = *(const bf16x8*)(smem + ra * 128 + (((ks * 4 + grp) ^ (ra & 7)) << 4));
        const int rb = wn * 64 + f * 16 + col;
        bfr[f] = *(const bf16x8*)(smem + 16384 + rb * 128 + (((ks * 4 + grp) ^ (rb & 7)) << 4));
      }
      #pragma unroll
      for (int i = 0; i < 4; ++i)
        #pragma unroll
        for (int j = 0; j < 4; ++j)
          acc[i][j] = MFMA16(af[i], bfr[j], acc[i][j]);
    }
  }
  const bool wv = WVT && (n0 >= 1024);
  if (!wv) {
    #pragma unroll
    for (int i = 0; i < 4; ++i)
      #pragma unroll
      for (int j = 0; j < 4; ++j) {
        const int n = n0 + wn * 64 + j * 16 + col;
        const float bz = bias[n];
        #pragma unroll
        for (int r = 0; r < 4; ++r) {
          const int m = m0 + wm * 64 + i * 16 + grp * 4 + r;
          const float v = acc[i][j][r] + bz;
          if (F32OUT)
            ((float*)Cv)[(size_t)m * N + n] = v;
          else
            ((bf16*)Cv)[(size_t)m * N + n] = __float2bfloat16(v);
        }
      }
  } else {
    __syncthreads();  // all waves done with K-loop LDS reads
    bf16* lt = (bf16*)smem;
    #pragma unroll
    for (int i = 0; i < 4; ++i)
      #pragma unroll
      for (int j = 0; j < 4; ++j) {
        const int nl = wn * 64 + j * 16 + col;
        const float bz = bias[n0 + nl];
        #pragma unroll
        for (int r = 0; r < 4; ++r) {
          const int ml = wm * 64 + i * 16 + grp * 4 + r;
          lt[nl * 136 + (ml ^ ((nl & 7) << 4))] = __float2bfloat16(acc[i][j][r] + bz);
        }
      }
    __syncthreads();
    const int row = tid >> 1, half = tid & 1;
    const int b = m0 >> 13, t0 = m0 & 8191;
    bf16* dst = vt + (size_t)(b * DM + (n0 & 511) + row) * TS + t0 + half * 64;
    const bf16* srcl = lt + row * 136;
    #pragma unroll
    for (int c = 0; c < 8; ++c)
      *(bf16x8*)(dst + c * 8) =
          *(const bf16x8*)(srcl + ((half * 64 + c * 8) ^ ((row & 7) << 4)));
  }
}

// --------------------------------------------------------------- vgt --------
// vgt[(b*NH+h)*HD+dv][g] = vt[row][gidx[g]]; zeroes vt front/tail pads.
__global__ void vgt_kernel(const bf16* __restrict__ vt, const int* __restrict__ gidx,
                           bf16* __restrict__ vtp, bf16* __restrict__ vgt) {
  const int64_t stride = (int64_t)gridDim.x * blockDim.x;
  const int64_t i0 = (int64_t)blockIdx.x * blockDim.x + threadIdx.x;
  for (int64_t i = i0; i < 512; i += stride) {
    if (i < 64) vtp[i - 64] = __float2bfloat16(0.f);
    else vtp[(size_t)2048 * TS + (i - 64)] = __float2bfloat16(0.f);
  }
  for (int64_t i = i0; i < (int64_t)2048 * NG; i += stride) {
    const int row = (int)(i >> 6), g = (int)(i & 63);
    const int gi = gidx[g];
    vgt[i] = vt[(size_t)row * TS + gi];
  }
}

// --------------------------------------------------------------- attn -------
// Block = 64 queries of one (b,h); 4 waves x 16 queries.
// LDS (single 50176 B buffer, sP overlays sK/sKg after a barrier):
//   sV  [32][216]   V^T window               (13824 B)
//   sVg [32][88]    global V^T               ( 5632 B)
//   sK  [192][32]   local K, XOR slot swizzle(12288 B)  <-+ overlaid by
//   sKg [64][32]    global K, XOR swizzle    ( 4096 B)  <-+ sP [4][16*240] (30720 B)
__global__ __launch_bounds__(256) void attn_kernel(const bf16* __restrict__ qkv,
                                                   const bf16* __restrict__ vt,
                                                   const bf16* __restrict__ vgt,
                                                   const int* __restrict__ gidx,
                                                   bf16* __restrict__ ctx) {
  constexpr int PROW = 240;  // row offset = 120 dwords == 24 mod 32 -> grp bank
                             // offsets {0,24,16,8}: conflict-free P writes
  constexpr int VST = 216;
  constexpr int VGST = 88;
  __shared__ __attribute__((aligned(16))) char smem[50176];
  bf16* sV = (bf16*)smem;
  bf16* sVg = (bf16*)(smem + 13824);
  bf16* sK = (bf16*)(smem + 19456);
  bf16* sKg = (bf16*)(smem + 31744);
  bf16* sP = (bf16*)(smem + 19456);  // overlay

  const int tid = threadIdx.x, wid = tid >> 6, lane = tid & 63;
  const int grp = lane >> 4, col = lane & 15;
  const int bid = (blockIdx.x & 7) * 1024 + (blockIdx.x >> 3);
  const int tile = bid & 127, h = (bid >> 7) & 15, b = bid >> 11;
  const int t0b = tile * 64;
  const int kbb = t0b - 64;
  const int bh = b * NH + h;
  const bf16* base = qkv + (size_t)b * TS * NQKV;
  const bf16* kpl = base + 512 + h * 32;

  // ---- cooperative staging ----
  #pragma unroll
  for (int it = 0; it < 3; ++it) {             // sK: 768 16B chunks, direct-to-LDS
    const int idx = it * 256 + tid;
    const int row = idx >> 2, part = idx & 3;
    const int tok = min(max(kbb + row, 0), TS - 1);
    gl_lds16(kpl + (size_t)tok * NQKV + ((part ^ (row & 3)) << 3), sK + idx * 8);
  }
  {
    const int row = tid >> 2, part = tid & 3;  // sKg: 256 chunks, direct-to-LDS
    const int gi = gidx[row];
    gl_lds16(kpl + (size_t)gi * NQKV + ((part ^ (row & 3)) << 3), sKg + tid * 8);
  }
  {
    const bf16* vr = vt + (size_t)(bh * HD + (tid >> 3)) * TS + kbb;
    #pragma unroll
    for (int i = 0; i < 4; ++i) {              // sV: 32 rows x 27 chunks
      const int c = i * 8 + (tid & 7);
      if (c < 27) *(bf16x8*)(sV + (tid >> 3) * VST + c * 8) = ld8(vr + c * 8);
    }
  }
  {
    const int row = tid >> 3, c = tid & 7;     // sVg: 256 chunks
    *(bf16x8*)(sVg + row * VGST + c * 8) = ld8(vgt + (size_t)(bh * HD + row) * NG + c * 8);
  }
  __syncthreads();

  // ---- per-wave compute ----
  const int qt = t0b + wid * 16;
  const int offw = wid * 16;
  bf16* myP = sP + wid * 16 * PROW;

  const bf16x8 qf = ld8(base + (size_t)(qt + col) * NQKV + h * 32 + grp * 8);
  const f32x4 z = {0.f, 0.f, 0.f, 0.f};
  f32x4 s[13];
  #pragma unroll
  for (int f = 0; f < 9; ++f) {
    const int row = offw + f * 16 + col;
    bf16x8 kf = ld8(sK + row * 32 + ((grp ^ (row & 3)) << 3));
    s[f] = MFMA16(qf, kf, z);
  }
  #pragma unroll
  for (int f = 0; f < 4; ++f) {
    const int row = f * 16 + col;
    bf16x8 kf = ld8(sKg + row * 32 + ((grp ^ (row & 3)) << 3));
    s[9 + f] = MFMA16(qf, kf, z);
  }
  const float scale = 0.17677669529663688f;  // 1/sqrt(32)
  float mx[4] = {-3e38f, -3e38f, -3e38f, -3e38f};
  const bool interior = (tile >= 1) & (tile <= 126);
  if (interior) {
    // band masks reduce to: f==0 -> col>=q, f==8 -> col<=q; f=1..7 all valid.
    #pragma unroll
    for (int f = 0; f < 13; ++f) {
      #pragma unroll
      for (int r = 0; r < 4; ++r) {
        float v = s[f][r] * scale;
        if (f == 0) v = (col >= grp * 4 + r) ? v : -1e30f;
        if (f == 8) v = (col <= grp * 4 + r) ? v : -1e30f;
        s[f][r] = v;
        mx[r] = fmaxf(mx[r], v);
      }
    }
  } else {
    #pragma unroll
    for (int f = 0; f < 13; ++f) {
      #pragma unroll
      for (int r = 0; r < 4; ++r) {
        float v = s[f][r] * scale;
        if (f < 9) {
          const int q = grp * 4 + r;
          const int j = f * 16 + col;
          const int pos = qt - 64 + j;
          const bool valid = (j >= q) & (j <= q + 128) & (pos >= 0) & (pos < TS);
          v = valid ? v : -1e30f;
        }
        s[f][r] = v;
        mx[r] = fmaxf(mx[r], v);
      }
    }
  }
  #pragma unroll
  for (int r = 0; r < 4; ++r) {
    #pragma unroll
    for (int d = 1; d < 16; d <<= 1) mx[r] = fmaxf(mx[r], __shfl_xor(mx[r], d));
  }
  float sm[4] = {0.f, 0.f, 0.f, 0.f};
  #pragma unroll
  for (int f = 0; f < 13; ++f) {
    #pragma unroll
    for (int r = 0; r < 4; ++r) {
      float p = __expf(s[f][r] - mx[r]);
      s[f][r] = p;
      sm[r] += p;
    }
  }
  #pragma unroll
  for (int r = 0; r < 4; ++r) {
    #pragma unroll
    for (int d = 1; d < 16; d <<= 1) sm[r] += __shfl_xor(sm[r], d);
    sm[r] = 1.0f / sm[r];
  }
  __syncthreads();  // all waves done reading sK/sKg; safe to overlay with sP

  // write P: local frags at j=f*16, zero pad at 144..159, global at 160..223
  #pragma unroll
  for (int f = 0; f < 13; ++f) {
    const int j = f * 16 + col + ((f >= 9) ? 16 : 0);
    #pragma unroll
    for (int r = 0; r < 4; ++r)
      myP[(grp * 4 + r) * PROW + j] = __float2bfloat16(s[f][r]);
  }
  #pragma unroll
  for (int r = 0; r < 4; ++r)
    myP[(grp * 4 + r) * PROW + 144 + col] = __float2bfloat16(0.f);
  __threadfence_block();

  f32x4 c0 = z, c1 = z;
  #pragma unroll
  for (int ks = 0; ks < 5; ++ks) {
    bf16x8 pa = ld8(myP + col * PROW + ks * 32 + grp * 8);
    const int kk = offw + ks * 32 + grp * 8;    // <= 207, within staged 216
    bf16x8 v0 = ld8(sV + col * VST + kk);
    bf16x8 v1 = ld8(sV + (col + 16) * VST + kk);
    c0 = MFMA16(pa, v0, c0);
    c1 = MFMA16(pa, v1, c1);
  }
  #pragma unroll
  for (int ks = 0; ks < 2; ++ks) {
    bf16x8 pa = ld8(myP + col * PROW + 160 + ks * 32 + grp * 8);
    bf16x8 v0 = ld8(sVg + col * VGST + ks * 32 + grp * 8);
    bf16x8 v1 = ld8(sVg + (col + 16) * VGST + ks * 32 + grp * 8);
    c0 = MFMA16(pa, v0, c0);
    c1 = MFMA16(pa, v1, c1);
  }
  #pragma unroll
  for (int r = 0; r < 4; ++r) {
    const int t = qt + grp * 4 + r;
    const size_t o = ((size_t)(b * TS + t)) * DM + h * 32;
    ctx[o + col] = __float2bfloat16(c0[r] * sm[r]);
    ctx[o + 16 + col] = __float2bfloat16(c1[r] * sm[r]);
  }
}

// ------------------------------------------------------------- launch -------
extern "C" void kernel_launch(void* const* d_in, const int* in_sizes, int n_in,
                              void* d_out, int out_size, void* d_ws, size_t ws_size,
                              hipStream_t stream) {
  (void)in_sizes; (void)n_in; (void)out_size; (void)ws_size;
  const float* x = (const float*)d_in[0];
  const float* Wq = (const float*)d_in[1];
  const float* bq = (const float*)d_in[2];
  const float* Wk = (const float*)d_in[3];
  const float* bk = (const float*)d_in[4];
  const float* Wv = (const float*)d_in[5];
  const float* bv = (const float*)d_in[6];
  const float* Wo = (const float*)d_in[7];
  const float* bo = (const float*)d_in[8];
  const int* gidx = (const int*)d_in[9];
  float* out = (float*)d_out;

  char* ws = (char*)d_ws;
  size_t off = 0;
  auto alloc = [&](size_t bytes) -> void* {
    void* p = ws + off;
    off += (bytes + 255) & ~(size_t)255;
    return p;
  };
  bf16* xb = (bf16*)alloc((size_t)BB * TS * DM * 2);       // 32 MB (reused as ctx)
  bf16* Wt = (bf16*)alloc((size_t)NQKV * DM * 2);          // 1.5 MB
  bf16* Wot = (bf16*)alloc((size_t)DM * DM * 2);           // 0.5 MB
  float* bqkv = (float*)alloc((size_t)NQKV * 4);           // 6 KB
  bf16* qkv = (bf16*)alloc((size_t)BB * TS * NQKV * 2);    // 96 MB (V third unused)
  bf16* vta = (bf16*)alloc(((size_t)2048 * TS + 512) * 2); // 32 MB + pad
  bf16* vgt = (bf16*)alloc((size_t)2048 * NG * 2);         // 256 KB
  bf16* ctx = xb;                                          // alias: xb dead after GEMM1
  bf16* vt = vta + 64;                                     // front pad of 64 elems

  prep_kernel<<<dim3(2048), dim3(256), 0, stream>>>(x, Wq, bq, Wk, bk, Wv, bv, Wo,
                                                    xb, Wt, Wot, bqkv);
  gemm_bias<false, true><<<dim3(3072), dim3(256), 0, stream>>>(xb, Wt, bqkv, qkv, vt,
                                                               BB * TS, NQKV, DM, 384);
  vgt_kernel<<<dim3(512), dim3(256), 0, stream>>>(vt, gidx, vt, vgt);
  attn_kernel<<<dim3(8192), dim3(256), 0, stream>>>(qkv, vt, vgt, gidx, ctx);
  gemm_bias<true, false><<<dim3(1024), dim3(256), 0, stream>>>(ctx, Wot, bo, out, nullptr,
                                                               BB * TS, DM, DM, 128);
}

// Round 5
// 195.454 us; speedup vs baseline: 1.6088x; 1.0765x over previous
//
#include <hip/hip_runtime.h>
#include <hip/hip_bf16.h>
#include <cstdint>
#include <cstddef>

using bf16 = __hip_bfloat16;
typedef __bf16 bf16x8 __attribute__((ext_vector_type(8)));
typedef float f32x4 __attribute__((ext_vector_type(4)));

constexpr int BB = 4;
constexpr int TS = 8192;
constexpr int NH = 16;
constexpr int HD = 32;
constexpr int DM = 512;      // NH*HD
constexpr int NQKV = 1536;   // 3*DM
constexpr int NG = 64;       // global tokens

#define MFMA16(a, b, c) __builtin_amdgcn_mfma_f32_16x16x32_bf16((a), (b), (c), 0, 0, 0)

__device__ __forceinline__ bf16x8 ld8(const bf16* p) { return *(const bf16x8*)p; }
__device__ __forceinline__ unsigned short b16bits(bf16 v) { return __builtin_bit_cast(unsigned short, v); }

__device__ __forceinline__ void gl_lds16(const bf16* g, void* l) {
  __builtin_amdgcn_global_load_lds((const __attribute__((address_space(1))) void*)g,
                                   (__attribute__((address_space(3))) void*)l, 16, 0, 0);
}

// ---------------------------------------------------------------- prep ------
__global__ void prep_kernel(const float* __restrict__ x,
                            const float* __restrict__ Wq, const float* __restrict__ bq,
                            const float* __restrict__ Wk, const float* __restrict__ bk,
                            const float* __restrict__ Wv, const float* __restrict__ bv,
                            const float* __restrict__ Wo,
                            bf16* __restrict__ xb, bf16* __restrict__ Wt,
                            bf16* __restrict__ Wot, float* __restrict__ bqkv) {
  const int64_t stride = (int64_t)gridDim.x * blockDim.x;
  const int64_t i0 = (int64_t)blockIdx.x * blockDim.x + threadIdx.x;
  const float4* x4 = (const float4*)x;
  ushort4* xb4 = (ushort4*)xb;
  for (int64_t i = i0; i < (int64_t)BB * TS * DM / 4; i += stride) {
    float4 v = x4[i];
    ushort4 o;
    o.x = b16bits(__float2bfloat16(v.x));
    o.y = b16bits(__float2bfloat16(v.y));
    o.z = b16bits(__float2bfloat16(v.z));
    o.w = b16bits(__float2bfloat16(v.w));
    xb4[i] = o;
  }
  for (int64_t i = i0; i < (int64_t)NQKV * DM; i += stride) {
    const int n = (int)(i >> 9), k = (int)(i & 511);
    const float* W = (n < 512) ? Wq : ((n < 1024) ? Wk : Wv);
    Wt[i] = __float2bfloat16(W[(size_t)k * DM + (n & 511)]);
  }
  for (int64_t i = i0; i < (int64_t)DM * DM; i += stride) {
    const int n = (int)(i >> 9), k = (int)(i & 511);
    Wot[i] = __float2bfloat16(Wo[(size_t)k * DM + n]);
  }
  for (int64_t i = i0; i < NQKV; i += stride)
    bqkv[i] = (i < 512) ? bq[i] : ((i < 1024) ? bk[i - 512] : bv[i - 1024]);
}

// ---------------------------------------------------------------- GEMM ------
// C[M,N] = A[M,K] @ Bt[N,K]^T + bias[N].  128x128 tile, BK=64, 4 waves.
// Double-buffered pipeline with counted vmcnt: tile kt+1's 8 global_load_lds
// are issued BEFORE waiting; s_waitcnt vmcnt(8) waits only tile kt's loads
// (issued a full K-step earlier); raw s_barrier avoids the compiler's
// vmcnt(0) drain. LDS = 2x16KB A + 2x16KB B = 64 KB.
// XCD-aware bid swizzle (grid divisible by 8; cpx = grid/8).
// WVT: for n0>=1024 (V third) the tile is transposed through LDS and written
// to vt[b*512 + (n&511)][t] in 128B-contiguous chunks (coalesced).
template <bool F32OUT, bool WVT>
__global__ __launch_bounds__(256) void gemm_bias(const bf16* __restrict__ A,
                                                 const bf16* __restrict__ Bt,
                                                 const float* __restrict__ bias,
                                                 void* __restrict__ Cv,
                                                 bf16* __restrict__ vt,
                                                 int M, int N, int K, int cpx) {
  __shared__ __attribute__((aligned(16))) char smem[65536];
  const int tid = threadIdx.x;
  const int lane = tid & 63, wid = tid >> 6;
  const int grp = lane >> 4, col = lane & 15;
  const int bid = (blockIdx.x & 7) * cpx + (blockIdx.x >> 3);
  const int NT = N >> 7;
  const int mt = bid / NT, nt = bid % NT;
  const int m0 = mt << 7, n0 = nt << 7;
  const int wm = wid >> 1, wn = wid & 1;
  f32x4 acc[4][4] = {};
  const int KT = K >> 6;

  auto stage = [&](int kt, int d) {
    #pragma unroll
    for (int c = 0; c < 4; ++c) {
      const int chunk = wid * 4 + c;              // 0..15, wave-uniform
      const int row = chunk * 8 + (lane >> 3);    // 0..127
      const int sl = lane & 7;                    // linear 16B slot in row
      const int koff = ((sl ^ (row & 7)) << 3) + (kt << 6);  // inverse-swizzled k
      gl_lds16(A + (size_t)(m0 + row) * K + koff, smem + d * 16384 + chunk * 1024);
      gl_lds16(Bt + (size_t)(n0 + row) * K + koff,
               smem + 32768 + d * 16384 + chunk * 1024);
    }
  };

  stage(0, 0);
  for (int kt = 0; kt < KT; ++kt) {
    const int cur = kt & 1;
    if (kt + 1 < KT) {
      stage(kt + 1, cur ^ 1);
      __builtin_amdgcn_sched_barrier(0);
      asm volatile("s_waitcnt vmcnt(8)" ::: "memory");  // tile kt's loads done
    } else {
      __builtin_amdgcn_sched_barrier(0);
      asm volatile("s_waitcnt vmcnt(0)" ::: "memory");
    }
    __builtin_amdgcn_sched_barrier(0);
    __builtin_amdgcn_s_barrier();              // all waves' tile-kt loads done
    __builtin_amdgcn_sched_barrier(0);
    const char* sA = smem + cur * 16384;
    const char* sB = smem + 32768 + cur * 16384;
    #pragma unroll
    for (int ks = 0; ks < 2; ++ks) {
      bf16x8 af[4], bfr[4];
      #pragma unroll
      for (int f = 0; f < 4; ++f) {
        const int ra = wm * 64 + f * 16 + col;
        af[f] = *(const bf16x8*)(sA + ra * 128 + (((ks * 4 + grp) ^ (ra & 7)) << 4));
        const int rb = wn * 64 + f * 16 + col;
        bfr[f] = *(const bf16x8*)(sB + rb * 128 + (((ks * 4 + grp) ^ (rb & 7)) << 4));
      }
      #pragma unroll
      for (int i = 0; i < 4; ++i)
        #pragma unroll
        for (int j = 0; j < 4; ++j)
          acc[i][j] = MFMA16(af[i], bfr[j], acc[i][j]);
    }
    __builtin_amdgcn_sched_barrier(0);
    __builtin_amdgcn_s_barrier();   // compute done; buf[cur] free for overwrite
    __builtin_amdgcn_sched_barrier(0);
  }
  const bool wv = WVT && (n0 >= 1024);
  if (!wv) {
    #pragma unroll
    for (int i = 0; i < 4; ++i)
      #pragma unroll
      for (int j = 0; j < 4; ++j) {
        const int n = n0 + wn * 64 + j * 16 + col;
        const float bz = bias[n];
        #pragma unroll
        for (int r = 0; r < 4; ++r) {
          const int m = m0 + wm * 64 + i * 16 + grp * 4 + r;
          const float v = acc[i][j][r] + bz;
          if (F32OUT)
            ((float*)Cv)[(size_t)m * N + n] = v;
          else
            ((bf16*)Cv)[(size_t)m * N + n] = __float2bfloat16(v);
        }
      }
  } else {
    __syncthreads();  // all waves done with K-loop LDS reads
    bf16* lt = (bf16*)smem;
    #pragma unroll
    for (int i = 0; i < 4; ++i)
      #pragma unroll
      for (int j = 0; j < 4; ++j) {
        const int nl = wn * 64 + j * 16 + col;
        const float bz = bias[n0 + nl];
        #pragma unroll
        for (int r = 0; r < 4; ++r) {
          const int ml = wm * 64 + i * 16 + grp * 4 + r;
          lt[nl * 136 + (ml ^ ((nl & 7) << 4))] = __float2bfloat16(acc[i][j][r] + bz);
        }
      }
    __syncthreads();
    const int row = tid >> 1, half = tid & 1;
    const int b = m0 >> 13, t0 = m0 & 8191;
    bf16* dst = vt + (size_t)(b * DM + (n0 & 511) + row) * TS + t0 + half * 64;
    const bf16* srcl = lt + row * 136;
    #pragma unroll
    for (int c = 0; c < 8; ++c)
      *(bf16x8*)(dst + c * 8) =
          *(const bf16x8*)(srcl + ((half * 64 + c * 8) ^ ((row & 7) << 4)));
  }
}

// --------------------------------------------------------------- vgt --------
// vgt[(b*NH+h)*HD+dv][g] = vt[row][gidx[g]]; zeroes vt front/tail pads.
__global__ void vgt_kernel(const bf16* __restrict__ vt, const int* __restrict__ gidx,
                           bf16* __restrict__ vtp, bf16* __restrict__ vgt) {
  const int64_t stride = (int64_t)gridDim.x * blockDim.x;
  const int64_t i0 = (int64_t)blockIdx.x * blockDim.x + threadIdx.x;
  for (int64_t i = i0; i < 512; i += stride) {
    if (i < 64) vtp[i - 64] = __float2bfloat16(0.f);
    else vtp[(size_t)2048 * TS + (i - 64)] = __float2bfloat16(0.f);
  }
  for (int64_t i = i0; i < (int64_t)2048 * NG; i += stride) {
    const int row = (int)(i >> 6), g = (int)(i & 63);
    const int gi = gidx[g];
    vgt[i] = vt[(size_t)row * TS + gi];
  }
}

// --------------------------------------------------------------- attn -------
// Block = 64 queries of one (b,h); 4 waves x 16 queries.
// LDS (single 50176 B buffer, sP overlays sK/sKg after a barrier):
//   sV  [32][216]   V^T window               (13824 B)
//   sVg [32][88]    global V^T               ( 5632 B)
//   sK  [192][32]   local K, XOR slot swizzle(12288 B)  <-+ overlaid by
//   sKg [64][32]    global K, XOR swizzle    ( 4096 B)  <-+ sP [4][16*240] (30720 B)
__global__ __launch_bounds__(256) void attn_kernel(const bf16* __restrict__ qkv,
                                                   const bf16* __restrict__ vt,
                                                   const bf16* __restrict__ vgt,
                                                   const int* __restrict__ gidx,
                                                   bf16* __restrict__ ctx) {
  constexpr int PROW = 240;  // row offset = 120 dwords == 24 mod 32 -> grp bank
                             // offsets {0,24,16,8}: conflict-free P writes
  constexpr int VST = 216;
  constexpr int VGST = 88;
  __shared__ __attribute__((aligned(16))) char smem[50176];
  bf16* sV = (bf16*)smem;
  bf16* sVg = (bf16*)(smem + 13824);
  bf16* sK = (bf16*)(smem + 19456);
  bf16* sKg = (bf16*)(smem + 31744);
  bf16* sP = (bf16*)(smem + 19456);  // overlay

  const int tid = threadIdx.x, wid = tid >> 6, lane = tid & 63;
  const int grp = lane >> 4, col = lane & 15;
  const int bid = (blockIdx.x & 7) * 1024 + (blockIdx.x >> 3);
  const int tile = bid & 127, h = (bid >> 7) & 15, b = bid >> 11;
  const int t0b = tile * 64;
  const int kbb = t0b - 64;
  const int bh = b * NH + h;
  const bf16* base = qkv + (size_t)b * TS * NQKV;
  const bf16* kpl = base + 512 + h * 32;

  // ---- cooperative staging ----
  #pragma unroll
  for (int it = 0; it < 3; ++it) {             // sK: 768 16B chunks, direct-to-LDS
    const int idx = it * 256 + tid;
    const int row = idx >> 2, part = idx & 3;
    const int tok = min(max(kbb + row, 0), TS - 1);
    gl_lds16(kpl + (size_t)tok * NQKV + ((part ^ (row & 3)) << 3), sK + idx * 8);
  }
  {
    const int row = tid >> 2, part = tid & 3;  // sKg: 256 chunks, direct-to-LDS
    const int gi = gidx[row];
    gl_lds16(kpl + (size_t)gi * NQKV + ((part ^ (row & 3)) << 3), sKg + tid * 8);
  }
  {
    const bf16* vr = vt + (size_t)(bh * HD + (tid >> 3)) * TS + kbb;
    #pragma unroll
    for (int i = 0; i < 4; ++i) {              // sV: 32 rows x 27 chunks
      const int c = i * 8 + (tid & 7);
      if (c < 27) *(bf16x8*)(sV + (tid >> 3) * VST + c * 8) = ld8(vr + c * 8);
    }
  }
  {
    const int row = tid >> 3, c = tid & 7;     // sVg: 256 chunks
    *(bf16x8*)(sVg + row * VGST + c * 8) = ld8(vgt + (size_t)(bh * HD + row) * NG + c * 8);
  }
  __syncthreads();

  // ---- per-wave compute ----
  const int qt = t0b + wid * 16;
  const int offw = wid * 16;
  bf16* myP = sP + wid * 16 * PROW;

  const bf16x8 qf = ld8(base + (size_t)(qt + col) * NQKV + h * 32 + grp * 8);
  const f32x4 z = {0.f, 0.f, 0.f, 0.f};
  f32x4 s[13];
  #pragma unroll
  for (int f = 0; f < 9; ++f) {
    const int row = offw + f * 16 + col;
    bf16x8 kf = ld8(sK + row * 32 + ((grp ^ (row & 3)) << 3));
    s[f] = MFMA16(qf, kf, z);
  }
  #pragma unroll
  for (int f = 0; f < 4; ++f) {
    const int row = f * 16 + col;
    bf16x8 kf = ld8(sKg + row * 32 + ((grp ^ (row & 3)) << 3));
    s[9 + f] = MFMA16(qf, kf, z);
  }
  const float scale = 0.17677669529663688f;  // 1/sqrt(32)
  float mx[4] = {-3e38f, -3e38f, -3e38f, -3e38f};
  const bool interior = (tile >= 1) & (tile <= 126);
  if (interior) {
    // band masks reduce to: f==0 -> col>=q, f==8 -> col<=q; f=1..7 all valid.
    #pragma unroll
    for (int f = 0; f < 13; ++f) {
      #pragma unroll
      for (int r = 0; r < 4; ++r) {
        float v = s[f][r] * scale;
        if (f == 0) v = (col >= grp * 4 + r) ? v : -1e30f;
        if (f == 8) v = (col <= grp * 4 + r) ? v : -1e30f;
        s[f][r] = v;
        mx[r] = fmaxf(mx[r], v);
      }
    }
  } else {
    #pragma unroll
    for (int f = 0; f < 13; ++f) {
      #pragma unroll
      for (int r = 0; r < 4; ++r) {
        float v = s[f][r] * scale;
        if (f < 9) {
          const int q = grp * 4 + r;
          const int j = f * 16 + col;
          const int pos = qt - 64 + j;
          const bool valid = (j >= q) & (j <= q + 128) & (pos >= 0) & (pos < TS);
          v = valid ? v : -1e30f;
        }
        s[f][r] = v;
        mx[r] = fmaxf(mx[r], v);
      }
    }
  }
  #pragma unroll
  for (int r = 0; r < 4; ++r) {
    #pragma unroll
    for (int d = 1; d < 16; d <<= 1) mx[r] = fmaxf(mx[r], __shfl_xor(mx[r], d));
  }
  float sm[4] = {0.f, 0.f, 0.f, 0.f};
  #pragma unroll
  for (int f = 0; f < 13; ++f) {
    #pragma unroll
    for (int r = 0; r < 4; ++r) {
      float p = __expf(s[f][r] - mx[r]);
      s[f][r] = p;
      sm[r] += p;
    }
  }
  #pragma unroll
  for (int r = 0; r < 4; ++r) {
    #pragma unroll
    for (int d = 1; d < 16; d <<= 1) sm[r] += __shfl_xor(sm[r], d);
    sm[r] = 1.0f / sm[r];
  }
  __syncthreads();  // all waves done reading sK/sKg; safe to overlay with sP

  // write P: local frags at j=f*16, zero pad at 144..159, global at 160..223
  #pragma unroll
  for (int f = 0; f < 13; ++f) {
    const int j = f * 16 + col + ((f >= 9) ? 16 : 0);
    #pragma unroll
    for (int r = 0; r < 4; ++r)
      myP[(grp * 4 + r) * PROW + j] = __float2bfloat16(s[f][r]);
  }
  #pragma unroll
  for (int r = 0; r < 4; ++r)
    myP[(grp * 4 + r) * PROW + 144 + col] = __float2bfloat16(0.f);
  __threadfence_block();

  f32x4 c0 = z, c1 = z;
  #pragma unroll
  for (int ks = 0; ks < 5; ++ks) {
    bf16x8 pa = ld8(myP + col * PROW + ks * 32 + grp * 8);
    const int kk = offw + ks * 32 + grp * 8;    // <= 207, within staged 216
    bf16x8 v0 = ld8(sV + col * VST + kk);
    bf16x8 v1 = ld8(sV + (col + 16) * VST + kk);
    c0 = MFMA16(pa, v0, c0);
    c1 = MFMA16(pa, v1, c1);
  }
  #pragma unroll
  for (int ks = 0; ks < 2; ++ks) {
    bf16x8 pa = ld8(myP + col * PROW + 160 + ks * 32 + grp * 8);
    bf16x8 v0 = ld8(sVg + col * VGST + ks * 32 + grp * 8);
    bf16x8 v1 = ld8(sVg + (col + 16) * VGST + ks * 32 + grp * 8);
    c0 = MFMA16(pa, v0, c0);
    c1 = MFMA16(pa, v1, c1);
  }
  #pragma unroll
  for (int r = 0; r < 4; ++r) {
    const int t = qt + grp * 4 + r;
    const size_t o = ((size_t)(b * TS + t)) * DM + h * 32;
    ctx[o + col] = __float2bfloat16(c0[r] * sm[r]);
    ctx[o + 16 + col] = __float2bfloat16(c1[r] * sm[r]);
  }
}

// ------------------------------------------------------------- launch -------
extern "C" void kernel_launch(void* const* d_in, const int* in_sizes, int n_in,
                              void* d_out, int out_size, void* d_ws, size_t ws_size,
                              hipStream_t stream) {
  (void)in_sizes; (void)n_in; (void)out_size; (void)ws_size;
  const float* x = (const float*)d_in[0];
  const float* Wq = (const float*)d_in[1];
  const float* bq = (const float*)d_in[2];
  const float* Wk = (const float*)d_in[3];
  const float* bk = (const float*)d_in[4];
  const float* Wv = (const float*)d_in[5];
  const float* bv = (const float*)d_in[6];
  const float* Wo = (const float*)d_in[7];
  const float* bo = (const float*)d_in[8];
  const int* gidx = (const int*)d_in[9];
  float* out = (float*)d_out;

  char* ws = (char*)d_ws;
  size_t off = 0;
  auto alloc = [&](size_t bytes) -> void* {
    void* p = ws + off;
    off += (bytes + 255) & ~(size_t)255;
    return p;
  };
  bf16* xb = (bf16*)alloc((size_t)BB * TS * DM * 2);       // 32 MB (reused as ctx)
  bf16* Wt = (bf16*)alloc((size_t)NQKV * DM * 2);          // 1.5 MB
  bf16* Wot = (bf16*)alloc((size_t)DM * DM * 2);           // 0.5 MB
  float* bqkv = (float*)alloc((size_t)NQKV * 4);           // 6 KB
  bf16* qkv = (bf16*)alloc((size_t)BB * TS * NQKV * 2);    // 96 MB (V third unused)
  bf16* vta = (bf16*)alloc(((size_t)2048 * TS + 512) * 2); // 32 MB + pad
  bf16* vgt = (bf16*)alloc((size_t)2048 * NG * 2);         // 256 KB
  bf16* ctx = xb;                                          // alias: xb dead after GEMM1
  bf16* vt = vta + 64;                                     // front pad of 64 elems

  prep_kernel<<<dim3(2048), dim3(256), 0, stream>>>(x, Wq, bq, Wk, bk, Wv, bv, Wo,
                                                    xb, Wt, Wot, bqkv);
  gemm_bias<false, true><<<dim3(3072), dim3(256), 0, stream>>>(xb, Wt, bqkv, qkv, vt,
                                                               BB * TS, NQKV, DM, 384);
  vgt_kernel<<<dim3(512), dim3(256), 0, stream>>>(vt, gidx, vt, vgt);
  attn_kernel<<<dim3(8192), dim3(256), 0, stream>>>(qkv, vt, vgt, gidx, ctx);
  gemm_bias<true, false><<<dim3(1024), dim3(256), 0, stream>>>(ctx, Wot, bo, out, nullptr,
                                                               BB * TS, DM, DM, 128);
}

// Round 6
// 172.846 us; speedup vs baseline: 1.8192x; 1.1308x over previous
//
#include <hip/hip_runtime.h>
#include <hip/hip_bf16.h>
#include <cstdint>
#include <cstddef>

using bf16 = __hip_bfloat16;
typedef __bf16 bf16x8 __attribute__((ext_vector_type(8)));
typedef __bf16 bf16x4 __attribute__((ext_vector_type(4)));
typedef float f32x4 __attribute__((ext_vector_type(4)));

constexpr int BB = 4;
constexpr int TS = 8192;
constexpr int NH = 16;
constexpr int HD = 32;
constexpr int DM = 512;      // NH*HD
constexpr int NQKV = 1536;   // 3*DM
constexpr int NG = 64;       // global tokens

#define MFMA16(a, b, c) __builtin_amdgcn_mfma_f32_16x16x32_bf16((a), (b), (c), 0, 0, 0)

__device__ __forceinline__ bf16x8 ld8(const bf16* p) { return *(const bf16x8*)p; }
__device__ __forceinline__ bf16x4 ld4(const bf16* p) { return *(const bf16x4*)p; }
__device__ __forceinline__ unsigned short b16bits(bf16 v) { return __builtin_bit_cast(unsigned short, v); }

__device__ __forceinline__ void gl_lds16(const bf16* g, void* l) {
  __builtin_amdgcn_global_load_lds((const __attribute__((address_space(1))) void*)g,
                                   (__attribute__((address_space(3))) void*)l, 16, 0, 0);
}

// ---------------------------------------------------------------- prep ------
__global__ void prep_kernel(const float* __restrict__ x,
                            const float* __restrict__ Wq, const float* __restrict__ bq,
                            const float* __restrict__ Wk, const float* __restrict__ bk,
                            const float* __restrict__ Wv, const float* __restrict__ bv,
                            const float* __restrict__ Wo,
                            bf16* __restrict__ xb, bf16* __restrict__ Wt,
                            bf16* __restrict__ Wot, float* __restrict__ bqkv) {
  const int64_t stride = (int64_t)gridDim.x * blockDim.x;
  const int64_t i0 = (int64_t)blockIdx.x * blockDim.x + threadIdx.x;
  const float4* x4 = (const float4*)x;
  ushort4* xb4 = (ushort4*)xb;
  for (int64_t i = i0; i < (int64_t)BB * TS * DM / 4; i += stride) {
    float4 v = x4[i];
    ushort4 o;
    o.x = b16bits(__float2bfloat16(v.x));
    o.y = b16bits(__float2bfloat16(v.y));
    o.z = b16bits(__float2bfloat16(v.z));
    o.w = b16bits(__float2bfloat16(v.w));
    xb4[i] = o;
  }
  for (int64_t i = i0; i < (int64_t)NQKV * DM; i += stride) {
    const int n = (int)(i >> 9), k = (int)(i & 511);
    const float* W = (n < 512) ? Wq : ((n < 1024) ? Wk : Wv);
    Wt[i] = __float2bfloat16(W[(size_t)k * DM + (n & 511)]);
  }
  for (int64_t i = i0; i < (int64_t)DM * DM; i += stride) {
    const int n = (int)(i >> 9), k = (int)(i & 511);
    Wot[i] = __float2bfloat16(Wo[(size_t)k * DM + n]);
  }
  for (int64_t i = i0; i < NQKV; i += stride)
    bqkv[i] = (i < 512) ? bq[i] : ((i < 1024) ? bk[i - 512] : bv[i - 1024]);
}

// ---------------------------------------------------------------- GEMM ------
// C[M,N] = A[M,K] @ Bt[N,K]^T + bias[N].  128x128 tile, BK=64, 4 waves.
// Double-buffered pipeline with counted vmcnt (see round-4 notes).
template <bool F32OUT, bool WVT>
__global__ __launch_bounds__(256) void gemm_bias(const bf16* __restrict__ A,
                                                 const bf16* __restrict__ Bt,
                                                 const float* __restrict__ bias,
                                                 void* __restrict__ Cv,
                                                 bf16* __restrict__ vt,
                                                 int M, int N, int K, int cpx) {
  __shared__ __attribute__((aligned(16))) char smem[65536];
  const int tid = threadIdx.x;
  const int lane = tid & 63, wid = tid >> 6;
  const int grp = lane >> 4, col = lane & 15;
  const int bid = (blockIdx.x & 7) * cpx + (blockIdx.x >> 3);
  const int NT = N >> 7;
  const int mt = bid / NT, nt = bid % NT;
  const int m0 = mt << 7, n0 = nt << 7;
  const int wm = wid >> 1, wn = wid & 1;
  f32x4 acc[4][4] = {};
  const int KT = K >> 6;

  auto stage = [&](int kt, int d) {
    #pragma unroll
    for (int c = 0; c < 4; ++c) {
      const int chunk = wid * 4 + c;              // 0..15, wave-uniform
      const int row = chunk * 8 + (lane >> 3);    // 0..127
      const int sl = lane & 7;                    // linear 16B slot in row
      const int koff = ((sl ^ (row & 7)) << 3) + (kt << 6);  // inverse-swizzled k
      gl_lds16(A + (size_t)(m0 + row) * K + koff, smem + d * 16384 + chunk * 1024);
      gl_lds16(Bt + (size_t)(n0 + row) * K + koff,
               smem + 32768 + d * 16384 + chunk * 1024);
    }
  };

  stage(0, 0);
  for (int kt = 0; kt < KT; ++kt) {
    const int cur = kt & 1;
    if (kt + 1 < KT) {
      stage(kt + 1, cur ^ 1);
      __builtin_amdgcn_sched_barrier(0);
      asm volatile("s_waitcnt vmcnt(8)" ::: "memory");  // tile kt's loads done
    } else {
      __builtin_amdgcn_sched_barrier(0);
      asm volatile("s_waitcnt vmcnt(0)" ::: "memory");
    }
    __builtin_amdgcn_sched_barrier(0);
    __builtin_amdgcn_s_barrier();              // all waves' tile-kt loads done
    __builtin_amdgcn_sched_barrier(0);
    const char* sA = smem + cur * 16384;
    const char* sB = smem + 32768 + cur * 16384;
    #pragma unroll
    for (int ks = 0; ks < 2; ++ks) {
      bf16x8 af[4], bfr[4];
      #pragma unroll
      for (int f = 0; f < 4; ++f) {
        const int ra = wm * 64 + f * 16 + col;
        af[f] = *(const bf16x8*)(sA + ra * 128 + (((ks * 4 + grp) ^ (ra & 7)) << 4));
        const int rb = wn * 64 + f * 16 + col;
        bfr[f] = *(const bf16x8*)(sB + rb * 128 + (((ks * 4 + grp) ^ (rb & 7)) << 4));
      }
      #pragma unroll
      for (int i = 0; i < 4; ++i)
        #pragma unroll
        for (int j = 0; j < 4; ++j)
          acc[i][j] = MFMA16(af[i], bfr[j], acc[i][j]);
    }
    __builtin_amdgcn_sched_barrier(0);
    __builtin_amdgcn_s_barrier();   // compute done; buf[cur] free for overwrite
    __builtin_amdgcn_sched_barrier(0);
  }
  const bool wv = WVT && (n0 >= 1024);
  if (!wv) {
    #pragma unroll
    for (int i = 0; i < 4; ++i)
      #pragma unroll
      for (int j = 0; j < 4; ++j) {
        const int n = n0 + wn * 64 + j * 16 + col;
        const float bz = bias[n];
        #pragma unroll
        for (int r = 0; r < 4; ++r) {
          const int m = m0 + wm * 64 + i * 16 + grp * 4 + r;
          const float v = acc[i][j][r] + bz;
          if (F32OUT)
            ((float*)Cv)[(size_t)m * N + n] = v;
          else
            ((bf16*)Cv)[(size_t)m * N + n] = __float2bfloat16(v);
        }
      }
  } else {
    __syncthreads();  // all waves done with K-loop LDS reads
    bf16* lt = (bf16*)smem;
    #pragma unroll
    for (int i = 0; i < 4; ++i)
      #pragma unroll
      for (int j = 0; j < 4; ++j) {
        const int nl = wn * 64 + j * 16 + col;
        const float bz = bias[n0 + nl];
        #pragma unroll
        for (int r = 0; r < 4; ++r) {
          const int ml = wm * 64 + i * 16 + grp * 4 + r;
          lt[nl * 136 + (ml ^ ((nl & 7) << 4))] = __float2bfloat16(acc[i][j][r] + bz);
        }
      }
    __syncthreads();
    const int row = tid >> 1, half = tid & 1;
    const int b = m0 >> 13, t0 = m0 & 8191;
    bf16* dst = vt + (size_t)(b * DM + (n0 & 511) + row) * TS + t0 + half * 64;
    const bf16* srcl = lt + row * 136;
    #pragma unroll
    for (int c = 0; c < 8; ++c)
      *(bf16x8*)(dst + c * 8) =
          *(const bf16x8*)(srcl + ((half * 64 + c * 8) ^ ((row & 7) << 4)));
  }
}

// --------------------------------------------------------------- vgt --------
// vgt[(b*NH+h)*HD+dv][g] = vt[row][gidx[g]]; zeroes vt front/tail pads.
__global__ void vgt_kernel(const bf16* __restrict__ vt, const int* __restrict__ gidx,
                           bf16* __restrict__ vtp, bf16* __restrict__ vgt) {
  const int64_t stride = (int64_t)gridDim.x * blockDim.x;
  const int64_t i0 = (int64_t)blockIdx.x * blockDim.x + threadIdx.x;
  for (int64_t i = i0; i < 512; i += stride) {
    if (i < 64) vtp[i - 64] = __float2bfloat16(0.f);
    else vtp[(size_t)2048 * TS + (i - 64)] = __float2bfloat16(0.f);
  }
  for (int64_t i = i0; i < (int64_t)2048 * NG; i += stride) {
    const int row = (int)(i >> 6), g = (int)(i & 63);
    const int gi = gidx[g];
    vgt[i] = vt[(size_t)row * TS + gi];
  }
}

// --------------------------------------------------------------- attn -------
// Block = 64 queries of one (b,h); 4 waves x 16 queries. Swapped QK^T
// (s = mfma(K,Q)) puts each query's full score row on 4 lanes {col, col+16,
// col+32, col+48}: softmax = 2 shuffles, P stays IN REGISTERS (no LDS
// roundtrip). PV: 16x16x32 MFMA where abstract k = grp*8+{0..7} covers keys
// {f0*16+grp*4+0..3, f1*16+grp*4+0..3} in BOTH operands -> two 16-key blocks
// per MFMA, B-frag = lane's own packed P, A-frag = 2x ds_read_b64 from V^T.
// LDS 35840 B -> 4 blocks/CU:
//   sV  [32][216]  V^T window; sVg [32][88] global V^T
//   sK  [192][32]  local K (XOR slot swizzle); sKg [64][32] global K
__global__ __launch_bounds__(256) void attn_kernel(const bf16* __restrict__ qkv,
                                                   const bf16* __restrict__ vt,
                                                   const bf16* __restrict__ vgt,
                                                   const int* __restrict__ gidx,
                                                   bf16* __restrict__ ctx) {
  constexpr int VST = 216;
  constexpr int VGST = 88;
  __shared__ __attribute__((aligned(16))) char smem[35840];
  bf16* sV = (bf16*)smem;             // 13824 B
  bf16* sVg = (bf16*)(smem + 13824);  //  5632 B
  bf16* sK = (bf16*)(smem + 19456);   // 12288 B
  bf16* sKg = (bf16*)(smem + 31744);  //  4096 B

  const int tid = threadIdx.x, wid = tid >> 6, lane = tid & 63;
  const int grp = lane >> 4, col = lane & 15;
  const int bid = (blockIdx.x & 7) * 1024 + (blockIdx.x >> 3);
  const int tile = bid & 127, h = (bid >> 7) & 15, b = bid >> 11;
  const int t0b = tile * 64;
  const int kbb = t0b - 64;
  const int bh = b * NH + h;
  const bf16* base = qkv + (size_t)b * TS * NQKV;
  const bf16* kpl = base + 512 + h * 32;

  // ---- cooperative staging ----
  #pragma unroll
  for (int it = 0; it < 3; ++it) {             // sK: 768 16B chunks, direct-to-LDS
    const int idx = it * 256 + tid;
    const int row = idx >> 2, part = idx & 3;
    const int tok = min(max(kbb + row, 0), TS - 1);
    gl_lds16(kpl + (size_t)tok * NQKV + ((part ^ (row & 3)) << 3), sK + idx * 8);
  }
  {
    const int row = tid >> 2, part = tid & 3;  // sKg: 256 chunks, direct-to-LDS
    const int gi = gidx[row];
    gl_lds16(kpl + (size_t)gi * NQKV + ((part ^ (row & 3)) << 3), sKg + tid * 8);
  }
  {
    const bf16* vr = vt + (size_t)(bh * HD + (tid >> 3)) * TS + kbb;
    #pragma unroll
    for (int i = 0; i < 4; ++i) {              // sV: 32 rows x 27 chunks
      const int c = i * 8 + (tid & 7);
      if (c < 27) *(bf16x8*)(sV + (tid >> 3) * VST + c * 8) = ld8(vr + c * 8);
    }
  }
  {
    const int row = tid >> 3, c = tid & 7;     // sVg: 256 chunks
    *(bf16x8*)(sVg + row * VGST + c * 8) = ld8(vgt + (size_t)(bh * HD + row) * NG + c * 8);
  }
  __syncthreads();

  // ---- per-wave compute ----
  const int qt = t0b + wid * 16;
  const int offw = wid * 16;

  const bf16x8 qf = ld8(base + (size_t)(qt + col) * NQKV + h * 32 + grp * 8);
  const f32x4 z = {0.f, 0.f, 0.f, 0.f};
  f32x4 s[13];
  #pragma unroll
  for (int f = 0; f < 9; ++f) {
    const int row = offw + f * 16 + col;
    bf16x8 kf = ld8(sK + row * 32 + ((grp ^ (row & 3)) << 3));
    s[f] = MFMA16(kf, qf, z);   // swapped: D[key_local][q]
  }
  #pragma unroll
  for (int f = 0; f < 4; ++f) {
    const int row = f * 16 + col;
    bf16x8 kf = ld8(sKg + row * 32 + ((grp ^ (row & 3)) << 3));
    s[9 + f] = MFMA16(kf, qf, z);
  }
  // lane (grp,col): query q=col, local key j = f*16 + grp*4 + r
  const float scale = 0.17677669529663688f;  // 1/sqrt(32)
  float mx = -3e38f;
  const bool interior = (tile >= 1) & (tile <= 126);
  if (interior) {
    #pragma unroll
    for (int f = 0; f < 13; ++f) {
      #pragma unroll
      for (int r = 0; r < 4; ++r) {
        float v = s[f][r] * scale;
        if (f == 0) v = (grp * 4 + r >= col) ? v : -1e30f;
        if (f == 8) v = (grp * 4 + r <= col) ? v : -1e30f;
        s[f][r] = v;
        mx = fmaxf(mx, v);
      }
    }
  } else {
    #pragma unroll
    for (int f = 0; f < 13; ++f) {
      #pragma unroll
      for (int r = 0; r < 4; ++r) {
        float v = s[f][r] * scale;
        if (f < 9) {
          const int j = f * 16 + grp * 4 + r;
          const int pos = qt - 64 + j;
          const bool valid = (j >= col) & (j <= col + 128) & (pos >= 0) & (pos < TS);
          v = valid ? v : -1e30f;
        }
        s[f][r] = v;
        mx = fmaxf(mx, v);
      }
    }
  }
  mx = fmaxf(mx, __shfl_xor(mx, 16));
  mx = fmaxf(mx, __shfl_xor(mx, 32));
  float sum = 0.f;
  bf16x8 pb[7];  // pairs (0,1),(2,3),(4,5),(6,7),(8,zero),(9,10),(11,12)
  #pragma unroll
  for (int f = 0; f < 13; ++f) {
    const int pr = (f < 9) ? (f >> 1) : (5 + ((f - 9) >> 1));
    const int hf = (f < 9) ? (f & 1) : ((f - 9) & 1);
    #pragma unroll
    for (int r = 0; r < 4; ++r) {
      float p = __expf(s[f][r] - mx);
      sum += p;
      pb[pr][hf * 4 + r] = (__bf16)__float2bfloat16(p);
    }
  }
  #pragma unroll
  for (int r = 0; r < 4; ++r) pb[4][4 + r] = (__bf16)__float2bfloat16(0.f);
  sum += __shfl_xor(sum, 16);
  sum += __shfl_xor(sum, 32);
  const float sm = 1.0f / sum;

  f32x4 c0 = z, c1 = z;
  const bf16* sVr0 = sV + col * VST;
  const bf16* sVr1 = sV + (col + 16) * VST;
  #pragma unroll
  for (int i = 0; i < 5; ++i) {     // local key pairs (32 keys per MFMA)
    const int kk = offw + i * 32 + grp * 4;
    bf16x8 a0 = __builtin_shufflevector(ld4(sVr0 + kk), ld4(sVr0 + kk + 16),
                                        0, 1, 2, 3, 4, 5, 6, 7);
    bf16x8 a1 = __builtin_shufflevector(ld4(sVr1 + kk), ld4(sVr1 + kk + 16),
                                        0, 1, 2, 3, 4, 5, 6, 7);
    c0 = MFMA16(a0, pb[i], c0);
    c1 = MFMA16(a1, pb[i], c1);
  }
  const bf16* sVg0 = sVg + col * VGST;
  const bf16* sVg1 = sVg + (col + 16) * VGST;
  #pragma unroll
  for (int i = 0; i < 2; ++i) {     // global key pairs
    const int kk = i * 32 + grp * 4;
    bf16x8 a0 = __builtin_shufflevector(ld4(sVg0 + kk), ld4(sVg0 + kk + 16),
                                        0, 1, 2, 3, 4, 5, 6, 7);
    bf16x8 a1 = __builtin_shufflevector(ld4(sVg1 + kk), ld4(sVg1 + kk + 16),
                                        0, 1, 2, 3, 4, 5, 6, 7);
    c0 = MFMA16(a0, pb[5 + i], c0);
    c1 = MFMA16(a1, pb[5 + i], c1);
  }
  // lane (grp,col) holds ctx^T[dv = grp*4+r (+16)][q = col]
  const int t = qt + col;
  bf16* op = ctx + ((size_t)(b * TS + t)) * DM + h * 32 + grp * 4;
  ushort4 o0, o1;
  o0.x = b16bits(__float2bfloat16(c0[0] * sm));
  o0.y = b16bits(__float2bfloat16(c0[1] * sm));
  o0.z = b16bits(__float2bfloat16(c0[2] * sm));
  o0.w = b16bits(__float2bfloat16(c0[3] * sm));
  o1.x = b16bits(__float2bfloat16(c1[0] * sm));
  o1.y = b16bits(__float2bfloat16(c1[1] * sm));
  o1.z = b16bits(__float2bfloat16(c1[2] * sm));
  o1.w = b16bits(__float2bfloat16(c1[3] * sm));
  *(ushort4*)op = o0;
  *(ushort4*)(op + 16) = o1;
}

// ------------------------------------------------------------- launch -------
extern "C" void kernel_launch(void* const* d_in, const int* in_sizes, int n_in,
                              void* d_out, int out_size, void* d_ws, size_t ws_size,
                              hipStream_t stream) {
  (void)in_sizes; (void)n_in; (void)out_size; (void)ws_size;
  const float* x = (const float*)d_in[0];
  const float* Wq = (const float*)d_in[1];
  const float* bq = (const float*)d_in[2];
  const float* Wk = (const float*)d_in[3];
  const float* bk = (const float*)d_in[4];
  const float* Wv = (const float*)d_in[5];
  const float* bv = (const float*)d_in[6];
  const float* Wo = (const float*)d_in[7];
  const float* bo = (const float*)d_in[8];
  const int* gidx = (const int*)d_in[9];
  float* out = (float*)d_out;

  char* ws = (char*)d_ws;
  size_t off = 0;
  auto alloc = [&](size_t bytes) -> void* {
    void* p = ws + off;
    off += (bytes + 255) & ~(size_t)255;
    return p;
  };
  bf16* xb = (bf16*)alloc((size_t)BB * TS * DM * 2);       // 32 MB (reused as ctx)
  bf16* Wt = (bf16*)alloc((size_t)NQKV * DM * 2);          // 1.5 MB
  bf16* Wot = (bf16*)alloc((size_t)DM * DM * 2);           // 0.5 MB
  float* bqkv = (float*)alloc((size_t)NQKV * 4);           // 6 KB
  bf16* qkv = (bf16*)alloc((size_t)BB * TS * NQKV * 2);    // 96 MB (V third unused)
  bf16* vta = (bf16*)alloc(((size_t)2048 * TS + 512) * 2); // 32 MB + pad
  bf16* vgt = (bf16*)alloc((size_t)2048 * NG * 2);         // 256 KB
  bf16* ctx = xb;                                          // alias: xb dead after GEMM1
  bf16* vt = vta + 64;                                     // front pad of 64 elems

  prep_kernel<<<dim3(2048), dim3(256), 0, stream>>>(x, Wq, bq, Wk, bk, Wv, bv, Wo,
                                                    xb, Wt, Wot, bqkv);
  gemm_bias<false, true><<<dim3(3072), dim3(256), 0, stream>>>(xb, Wt, bqkv, qkv, vt,
                                                               BB * TS, NQKV, DM, 384);
  vgt_kernel<<<dim3(512), dim3(256), 0, stream>>>(vt, gidx, vt, vgt);
  attn_kernel<<<dim3(8192), dim3(256), 0, stream>>>(qkv, vt, vgt, gidx, ctx);
  gemm_bias<true, false><<<dim3(1024), dim3(256), 0, stream>>>(ctx, Wot, bo, out, nullptr,
                                                               BB * TS, DM, DM, 128);
}